// Round 3
// baseline (7572.891 us; speedup 1.0000x reference)
//
#include <hip/hip_runtime.h>
#include <math.h>

#define NB 8
#define CDCT 64
#define HB 128
#define WB 128
#define EE 128
#define NHD 4
#define KS 7
#define PP 49
#define DFF 512
#define NLAY 4
#define HW (HB*WB)          // 16384
#define NPOS (NB*HB*WB)     // 131072
#define EPSV 1e-5f

typedef unsigned short u16;

__device__ __forceinline__ float bf2f(u16 u) {
    union { unsigned int i; float f; } c; c.i = ((unsigned int)u) << 16; return c.f;
}
__device__ __forceinline__ u16 f2bf(float f) {
    union { float f; unsigned int i; } c; c.f = f;
    unsigned int x = c.i;
    return (u16)((x + 0x7fffu + ((x >> 16) & 1u)) >> 16);
}

// ---------------- Encoder: 3x3 conv (64->64) + bias, FiLM, result t = dct + qt*c1 ----------------
// t stored f32, NCHW layout. One block per (n,c,h); 128 threads = w.
__global__ __launch_bounds__(128) void k_enc_conv(
    const float* __restrict__ dct, const float* __restrict__ qt,
    const float* __restrict__ w1, const float* __restrict__ b1,
    float* __restrict__ t)
{
    int bid = blockIdx.x;            // n*64*128 + c*128 + h
    int h = bid & 127;
    int c = (bid >> 7) & 63;
    int n = bid >> 13;
    int w = threadIdx.x;
    __shared__ float wl[576];
    for (int idx = threadIdx.x; idx < 576; idx += 128) wl[idx] = w1[c * 576 + idx];
    __syncthreads();
    float acc = b1[c];
    const float* dn = dct + (size_t)n * CDCT * HW;
    for (int ci = 0; ci < 64; ++ci) {
        const float* dci = dn + (size_t)ci * HW;
        #pragma unroll
        for (int ki = 0; ki < 3; ++ki) {
            int hh = h + ki - 1;
            if (hh < 0 || hh >= HB) continue;
            const float* row = dci + hh * WB;
            const float* wr = &wl[ci * 9 + ki * 3];
            #pragma unroll
            for (int kj = 0; kj < 3; ++kj) {
                int ww = w + kj - 1;
                if (ww >= 0 && ww < WB) acc += row[ww] * wr[kj];
            }
        }
    }
    float qv = qt[n * CDCT + c];
    size_t off = ((size_t)(n * CDCT + c)) * HW + h * WB + w;
    t[off] = dct[off] + qv * acc;
}

// ---------------- Encoder 1x1: x[n,h,w,e] = sum_ci t[n,ci,h,w]*w2[e,ci] + b2[e] ----------------
// block 128 threads (= output channel e), 8 positions per block
__global__ __launch_bounds__(128) void k_enc_proj(
    const float* __restrict__ t, const float* __restrict__ w2,
    const float* __restrict__ b2, float* __restrict__ x)
{
    int pos0 = blockIdx.x * 8;
    int n = pos0 >> 14;
    int rowoff = pos0 & 16383;
    __shared__ float tl[64 * 8];      // [ci][p]
    const float* tb = t + (size_t)n * CDCT * HW + rowoff;
    for (int k = 0; k < 4; ++k) {
        int idx = k * 128 + threadIdx.x;   // 0..511
        int ci = idx >> 3, p = idx & 7;
        tl[ci * 8 + p] = tb[(size_t)ci * HW + p];
    }
    __syncthreads();
    int o = threadIdx.x;
    float bias = b2[o];
    float acc[8];
    #pragma unroll
    for (int p = 0; p < 8; ++p) acc[p] = bias;
    for (int ci = 0; ci < 64; ++ci) {
        float wv = w2[o * 64 + ci];
        #pragma unroll
        for (int p = 0; p < 8; ++p) acc[p] += tl[ci * 8 + p] * wv;
    }
    float* xo = x + (size_t)pos0 * EE + o;
    #pragma unroll
    for (int p = 0; p < 8; ++p) xo[(size_t)p * EE] = acc[p];
}

// ---------------- LN1 + QKV projection (q,k,v out in bf16 internal) ----------------
// block 128 threads (= output channel), 8 positions per block
__global__ __launch_bounds__(128) void k_qkv(
    const float* __restrict__ x,
    const float* __restrict__ g, const float* __restrict__ b,
    const float* __restrict__ wq, const float* __restrict__ bq,
    const float* __restrict__ wk, const float* __restrict__ bk,
    const float* __restrict__ wv, const float* __restrict__ bv,
    u16* __restrict__ qo, u16* __restrict__ ko, u16* __restrict__ vo)
{
    int pos0 = blockIdx.x * 8;
    int tid = threadIdx.x;
    __shared__ float y0[8 * 128];
    __shared__ float red[2][2][8];
    float xv[8], s1[8], s2[8];
    #pragma unroll
    for (int p = 0; p < 8; ++p) {
        xv[p] = x[(size_t)(pos0 + p) * EE + tid];
        s1[p] = xv[p]; s2[p] = xv[p] * xv[p];
    }
    #pragma unroll
    for (int off = 32; off; off >>= 1) {
        #pragma unroll
        for (int p = 0; p < 8; ++p) {
            s1[p] += __shfl_xor(s1[p], off);
            s2[p] += __shfl_xor(s2[p], off);
        }
    }
    int wid = tid >> 6;
    if ((tid & 63) == 0) {
        #pragma unroll
        for (int p = 0; p < 8; ++p) { red[0][wid][p] = s1[p]; red[1][wid][p] = s2[p]; }
    }
    __syncthreads();
    float gg = g[tid], bb = b[tid];
    #pragma unroll
    for (int p = 0; p < 8; ++p) {
        float sum = red[0][0][p] + red[0][1][p];
        float sq  = red[1][0][p] + red[1][1][p];
        float m = sum * (1.0f / 128.0f);
        float var = sq * (1.0f / 128.0f) - m * m;
        float rstd = rsqrtf(var + EPSV);
        y0[p * 128 + tid] = (xv[p] - m) * rstd * gg + bb;
    }
    __syncthreads();
    float aq[8], ak[8], av[8];
    #pragma unroll
    for (int p = 0; p < 8; ++p) { aq[p] = 0.f; ak[p] = 0.f; av[p] = 0.f; }
    for (int i = 0; i < 128; ++i) {
        float wqv = wq[i * 128 + tid];
        float wkv = wk[i * 128 + tid];
        float wvv = wv[i * 128 + tid];
        #pragma unroll
        for (int p = 0; p < 8; ++p) {
            float y = y0[p * 128 + i];
            aq[p] += y * wqv; ak[p] += y * wkv; av[p] += y * wvv;
        }
    }
    float bqv = bq[tid], bkv = bk[tid], bvv = bv[tid];
    #pragma unroll
    for (int p = 0; p < 8; ++p) {
        size_t o = (size_t)(pos0 + p) * EE + tid;
        qo[o] = f2bf(aq[p] + bqv);
        ko[o] = f2bf(ak[p] + bkv);
        vo[o] = f2bf(av[p] + bvv);
    }
}

// ---------------- 7x7 sliding-window attention ----------------
// block (64,4): 64 consecutive w-positions, 4 heads. Thread = (position, head).
__global__ __launch_bounds__(256) void k_attn(
    const u16* __restrict__ q, const u16* __restrict__ k,
    const u16* __restrict__ v, const float* __restrict__ rb,
    float* __restrict__ y2)
{
    int pos0 = blockIdx.x * 64;
    int lane = threadIdx.x;      // 0..63
    int hd = threadIdx.y;        // 0..3
    int n = pos0 >> 14;
    int hrow = (pos0 & 16383) >> 7;
    int w = (pos0 & 127) + lane;
    __shared__ float rbl[NHD * PP];
    int tt = hd * 64 + lane;
    if (tt < NHD * PP) rbl[tt] = rb[tt];
    __syncthreads();
    const u16* qp = q + (size_t)(pos0 + lane) * EE + hd * 32;
    float qr[32];
    #pragma unroll
    for (int d4 = 0; d4 < 8; ++d4) {
        ushort4 u = *reinterpret_cast<const ushort4*>(qp + d4 * 4);
        qr[d4*4+0] = bf2f(u.x); qr[d4*4+1] = bf2f(u.y);
        qr[d4*4+2] = bf2f(u.z); qr[d4*4+3] = bf2f(u.w);
    }
    const float scale = 0.088388347648318447f; // 1/sqrt(128)
    float s[PP];
    float mx = -1e30f;
    #pragma unroll
    for (int di = 0; di < 7; ++di) {
        int hh = hrow + di - 3;
        #pragma unroll
        for (int dj = 0; dj < 7; ++dj) {
            int ww = w + dj - 3;
            int idx = di * 7 + dj;
            float sc = rbl[hd * PP + idx];
            if (hh >= 0 && hh < HB && ww >= 0 && ww < WB) {
                const u16* kp = k + ((size_t)n * HW + hh * WB + ww) * EE + hd * 32;
                float dot = 0.f;
                #pragma unroll
                for (int d4 = 0; d4 < 8; ++d4) {
                    ushort4 u = *reinterpret_cast<const ushort4*>(kp + d4 * 4);
                    dot += qr[d4*4+0]*bf2f(u.x) + qr[d4*4+1]*bf2f(u.y)
                         + qr[d4*4+2]*bf2f(u.z) + qr[d4*4+3]*bf2f(u.w);
                }
                sc += dot * scale;
            }
            s[idx] = sc;
            mx = fmaxf(mx, sc);
        }
    }
    float sum = 0.f;
    #pragma unroll
    for (int i = 0; i < PP; ++i) { float e_ = __expf(s[i] - mx); s[i] = e_; sum += e_; }
    float inv = 1.0f / sum;
    float acc[32];
    #pragma unroll
    for (int d = 0; d < 32; ++d) acc[d] = 0.f;
    #pragma unroll
    for (int di = 0; di < 7; ++di) {
        int hh = hrow + di - 3;
        if (hh < 0 || hh >= HB) continue;
        #pragma unroll
        for (int dj = 0; dj < 7; ++dj) {
            int ww = w + dj - 3;
            if (ww < 0 || ww >= WB) continue;
            float a = s[di * 7 + dj] * inv;
            const u16* vp = v + ((size_t)n * HW + hh * WB + ww) * EE + hd * 32;
            #pragma unroll
            for (int d4 = 0; d4 < 8; ++d4) {
                ushort4 u = *reinterpret_cast<const ushort4*>(vp + d4 * 4);
                acc[d4*4+0] += a * bf2f(u.x); acc[d4*4+1] += a * bf2f(u.y);
                acc[d4*4+2] += a * bf2f(u.z); acc[d4*4+3] += a * bf2f(u.w);
            }
        }
    }
    float* yo = y2 + (size_t)(pos0 + lane) * EE + hd * 32;
    #pragma unroll
    for (int d = 0; d < 32; ++d) yo[d] = acc[d];
}

// ---------------- LN2 + FF (gelu exact) + residual, x updated in place ----------------
// block 128 threads, 8 positions per block
__global__ __launch_bounds__(128) void k_ff(
    float* __restrict__ x, const float* __restrict__ y2,
    const float* __restrict__ g, const float* __restrict__ b,
    const float* __restrict__ w1, const float* __restrict__ b1,
    const float* __restrict__ w2, const float* __restrict__ b2)
{
    int pos0 = blockIdx.x * 8;
    int tid = threadIdx.x;
    __shared__ float y3[8 * 128];
    __shared__ float hbuf[8 * 512];
    __shared__ float red[2][2][8];
    float res[8], tv[8], s1[8], s2[8];
    #pragma unroll
    for (int p = 0; p < 8; ++p) {
        float xv = x[(size_t)(pos0 + p) * EE + tid];
        float yv = y2[(size_t)(pos0 + p) * EE + tid];
        res[p] = yv;
        tv[p] = xv + yv;
        s1[p] = tv[p]; s2[p] = tv[p] * tv[p];
    }
    #pragma unroll
    for (int off = 32; off; off >>= 1) {
        #pragma unroll
        for (int p = 0; p < 8; ++p) {
            s1[p] += __shfl_xor(s1[p], off);
            s2[p] += __shfl_xor(s2[p], off);
        }
    }
    int wid = tid >> 6;
    if ((tid & 63) == 0) {
        #pragma unroll
        for (int p = 0; p < 8; ++p) { red[0][wid][p] = s1[p]; red[1][wid][p] = s2[p]; }
    }
    __syncthreads();
    float gg = g[tid], bb = b[tid];
    #pragma unroll
    for (int p = 0; p < 8; ++p) {
        float sum = red[0][0][p] + red[0][1][p];
        float sq  = red[1][0][p] + red[1][1][p];
        float m = sum * (1.0f / 128.0f);
        float var = sq * (1.0f / 128.0f) - m * m;
        float rstd = rsqrtf(var + EPSV);
        y3[p * 128 + tid] = (tv[p] - m) * rstd * gg + bb;
    }
    __syncthreads();
    for (int jc = 0; jc < 4; ++jc) {
        int j = jc * 128 + tid;
        float bb1 = b1[j];
        float accB[8];
        #pragma unroll
        for (int p = 0; p < 8; ++p) accB[p] = bb1;
        for (int i = 0; i < 128; ++i) {
            float wv = w1[i * 512 + j];
            #pragma unroll
            for (int p = 0; p < 8; ++p) accB[p] += y3[p * 128 + i] * wv;
        }
        #pragma unroll
        for (int p = 0; p < 8; ++p) {
            float hx = accB[p];
            hbuf[p * 512 + j] = 0.5f * hx * (1.0f + erff(hx * 0.70710678118654752f));
        }
    }
    __syncthreads();
    float acc2[8];
    #pragma unroll
    for (int p = 0; p < 8; ++p) acc2[p] = 0.f;
    for (int j = 0; j < 512; ++j) {
        float wv = w2[j * 128 + tid];
        #pragma unroll
        for (int p = 0; p < 8; ++p) acc2[p] += hbuf[p * 512 + j] * wv;
    }
    float bb2 = b2[tid];
    #pragma unroll
    for (int p = 0; p < 8; ++p)
        x[(size_t)(pos0 + p) * EE + tid] = res[p] + acc2[p] + bb2;
}

// ---------------- Decoder: out = dct + (x @ dec_w^T + dec_b) * qt ----------------
// block (64,4): 64 positions, thread handles 16 output channels
__global__ __launch_bounds__(256) void k_dec(
    const float* __restrict__ x, const float* __restrict__ dct,
    const float* __restrict__ qt, const float* __restrict__ wd,
    const float* __restrict__ bd, float* __restrict__ out)
{
    int pos0 = blockIdx.x * 64;
    int lane = threadIdx.x;
    int gq = threadIdx.y;
    int n = pos0 >> 14;
    int hw0 = pos0 & 16383;
    __shared__ float xl[64 * 129];
    for (int kk = 0; kk < 32; ++kk) {
        int idx = kk * 256 + gq * 64 + lane;   // 0..8191
        int l = idx >> 7, e = idx & 127;
        xl[l * 129 + e] = x[(size_t)pos0 * EE + idx];
    }
    __syncthreads();
    for (int cc = 0; cc < 16; ++cc) {
        int co = gq * 16 + cc;
        float acc = 0.f;
        const float* wr = wd + co * 128;
        const float* xr = &xl[lane * 129];
        #pragma unroll
        for (int e4 = 0; e4 < 32; ++e4) {
            float4 u = *reinterpret_cast<const float4*>(wr + e4 * 4);
            acc += xr[e4*4+0]*u.x + xr[e4*4+1]*u.y
                 + xr[e4*4+2]*u.z + xr[e4*4+3]*u.w;
        }
        float qv = qt[n * CDCT + co];
        float r = (acc + bd[co]) * qv;
        size_t off = ((size_t)(n * CDCT + co)) * HW + hw0 + lane;
        out[off] = dct[off] + r;
    }
}

extern "C" void kernel_launch(void* const* d_in, const int* in_sizes, int n_in,
                              void* d_out, int out_size, void* d_ws, size_t ws_size,
                              hipStream_t stream) {
    const float* dct  = (const float*)d_in[0];
    const float* qt   = (const float*)d_in[1];
    const float* ec1w = (const float*)d_in[2];
    const float* ec1b = (const float*)d_in[3];
    const float* ec2w = (const float*)d_in[4];
    const float* ec2b = (const float*)d_in[5];
    const float* ln1g = (const float*)d_in[6];
    const float* ln1b = (const float*)d_in[7];
    const float* qw   = (const float*)d_in[8];
    const float* qb   = (const float*)d_in[9];
    const float* kw   = (const float*)d_in[10];
    const float* kb   = (const float*)d_in[11];
    const float* vw   = (const float*)d_in[12];
    const float* vb   = (const float*)d_in[13];
    const float* rb   = (const float*)d_in[14];
    const float* ln2g = (const float*)d_in[15];
    const float* ln2b = (const float*)d_in[16];
    const float* fw1  = (const float*)d_in[17];
    const float* fb1  = (const float*)d_in[18];
    const float* fw2  = (const float*)d_in[19];
    const float* fb2  = (const float*)d_in[20];
    const float* dw   = (const float*)d_in[21];
    const float* db   = (const float*)d_in[22];

    char* ws = (char*)d_ws;
    float* xbuf  = (float*)ws;                         // 67108864 B
    float* y2buf = (float*)(ws + 67108864);            // 67108864 B
    u16*   qbuf  = (u16*)(ws + 134217728);             // 33554432 B
    u16*   kbuf  = (u16*)(ws + 167772160);             // 33554432 B
    u16*   vbuf  = (u16*)(ws + 201326592);             // 33554432 B
    float* tbuf  = y2buf;                              // encoder temp (33.5MB < 67MB)

    k_enc_conv<<<dim3(NB * CDCT * HB), dim3(128), 0, stream>>>(dct, qt, ec1w, ec1b, tbuf);
    k_enc_proj<<<dim3(NPOS / 8), dim3(128), 0, stream>>>(tbuf, ec2w, ec2b, xbuf);
    for (int l = 0; l < NLAY; ++l) {
        k_qkv<<<dim3(NPOS / 8), dim3(128), 0, stream>>>(
            xbuf, ln1g + l * EE, ln1b + l * EE,
            qw + l * EE * EE, qb + l * EE,
            kw + l * EE * EE, kb + l * EE,
            vw + l * EE * EE, vb + l * EE,
            qbuf, kbuf, vbuf);
        k_attn<<<dim3(NPOS / 64), dim3(64, 4), 0, stream>>>(
            qbuf, kbuf, vbuf, rb + l * NHD * PP, y2buf);
        k_ff<<<dim3(NPOS / 8), dim3(128), 0, stream>>>(
            xbuf, y2buf, ln2g + l * EE, ln2b + l * EE,
            fw1 + l * EE * DFF, fb1 + l * DFF,
            fw2 + l * DFF * EE, fb2 + l * EE);
    }
    k_dec<<<dim3(NPOS / 64), dim3(64, 4), 0, stream>>>(
        xbuf, dct, qt, dw, db, (float*)d_out);
}

// Round 4
// 3814.122 us; speedup vs baseline: 1.9855x; 1.9855x over previous
//
#include <hip/hip_runtime.h>
#include <math.h>

#define NB 8
#define CDCT 64
#define HB 128
#define WB 128
#define EE 128
#define NHD 4
#define KS 7
#define PP 49
#define DFF 512
#define NLAY 4
#define HW (HB*WB)          // 16384
#define NPOS (NB*HB*WB)     // 131072
#define EPSV 1e-5f

typedef unsigned short u16;
typedef float f32x4 __attribute__((ext_vector_type(4)));
typedef short s16x8 __attribute__((ext_vector_type(8)));

__device__ __forceinline__ float bf2f(u16 u) {
    union { unsigned int i; float f; } c; c.i = ((unsigned int)u) << 16; return c.f;
}
__device__ __forceinline__ u16 f2bf(float f) {
    union { float f; unsigned int i; } c; c.f = f;
    unsigned int x = c.i;
    return (u16)((x + 0x7fffu + ((x >> 16) & 1u)) >> 16);
}
__device__ __forceinline__ void up2(unsigned int u, float& lo, float& hi) {
    union { unsigned int i; float f; } a, b;
    a.i = u << 16; b.i = u & 0xffff0000u;
    lo = a.f; hi = b.f;
}

// ============ prep: transpose+convert transformer weights to bf16 ============
// wqkvt[l][n(384)][k(128)]; w1t[l][j(512)][i(128)]; w2t[l][e(128)][d(512)]
__global__ __launch_bounds__(256) void k_prep_qkvff(
    const float* __restrict__ qw, const float* __restrict__ kw, const float* __restrict__ vw,
    const float* __restrict__ fw1, const float* __restrict__ fw2,
    u16* __restrict__ wqkvt, u16* __restrict__ w1t, u16* __restrict__ w2t)
{
    int idx = blockIdx.x * 256 + threadIdx.x;      // < 720896
    int l = idx / 180224;
    int rem = idx - l * 180224;
    if (rem < 49152) {
        int n = rem >> 7, k2 = rem & 127;
        int mat = n >> 7, c = n & 127;
        const float* src = (mat == 0) ? qw : (mat == 1) ? kw : vw;
        wqkvt[l * 49152 + rem] = f2bf(src[l * 16384 + k2 * 128 + c]);
    } else if (rem < 114688) {
        int r2 = rem - 49152;
        int j = r2 >> 7, i = r2 & 127;
        w1t[l * 65536 + r2] = f2bf(fw1[l * 65536 + i * 512 + j]);
    } else {
        int r3 = rem - 114688;
        int e = r3 >> 9, d = r3 & 511;
        w2t[l * 65536 + r3] = f2bf(fw2[l * 65536 + d * 128 + e]);
    }
}

// prep conv weights: [co][ci][12] bf16 (taps 0..8 + pad)
__global__ __launch_bounds__(256) void k_prep_conv(
    const float* __restrict__ ec1w, u16* __restrict__ convw)
{
    int idx = blockIdx.x * 256 + threadIdx.x;      // < 49152
    int co = idx / 768;
    int r = idx - co * 768;
    int ci = r / 12, tp = r - ci * 12;
    convw[idx] = (tp < 9) ? f2bf(ec1w[co * 576 + ci * 9 + tp]) : (u16)0;
}

// ============ Encoder conv 3x3 + FiLM: t = dct + qt*(conv(dct)+b1) ============
// block = (n, h, chalf): 32 co per block; input staged in 16-ci chunks.
__global__ __launch_bounds__(256) void k_enc_conv2(
    const float* __restrict__ dct, const float* __restrict__ qt,
    const u16* __restrict__ convw, const float* __restrict__ b1,
    float* __restrict__ t)
{
    int bid = blockIdx.x;
    int chalf = bid & 1;
    int h = (bid >> 1) & 127;
    int n = bid >> 8;
    int tid = threadIdx.x;
    int w = tid & 127;
    int s = __builtin_amdgcn_readfirstlane(tid >> 7);   // wave-uniform

    __shared__ u16 wlds[32 * 64 * 12];   // 49152 B
    __shared__ u16 inl[16][3][128];      // 12288 B

    // stage this block's 32-co weight slab
    {
        const uint4* src = (const uint4*)(convw + chalf * 32 * 768);
        uint4* dst = (uint4*)wlds;
        for (int i = tid; i < 3072; i += 256) dst[i] = src[i];
    }

    float acc[16];
    #pragma unroll
    for (int j = 0; j < 16; ++j) acc[j] = 0.f;

    for (int cc = 0; cc < 4; ++cc) {
        __syncthreads();
        // stage 16 ci x 3 rows x 128 w (bf16), zero OOB rows
        for (int idx = tid; idx < 6144; idx += 256) {
            int w2 = idx & 127;
            int rr = idx >> 7;             // 0..47
            int ciL = rr / 3, dh = rr - ciL * 3;
            int hh = h + dh - 1;
            float v = 0.f;
            if (hh >= 0 && hh < HB)
                v = dct[((size_t)(n * 64 + cc * 16 + ciL)) * HW + hh * WB + w2];
            inl[ciL][dh][w2] = f2bf(v);
        }
        __syncthreads();
        for (int ciL = 0; ciL < 16; ++ciL) {
            float iv[9];
            #pragma unroll
            for (int dh = 0; dh < 3; ++dh) {
                iv[dh * 3 + 0] = (w > 0)   ? bf2f(inl[ciL][dh][w - 1]) : 0.f;
                iv[dh * 3 + 1] =             bf2f(inl[ciL][dh][w]);
                iv[dh * 3 + 2] = (w < 127) ? bf2f(inl[ciL][dh][w + 1]) : 0.f;
            }
            int ci = cc * 16 + ciL;
            #pragma unroll 2
            for (int j = 0; j < 16; ++j) {
                const u16* wc = &wlds[((s * 16 + j) * 64 + ci) * 12];
                uint2 w01 = *(const uint2*)(wc);
                uint2 w23 = *(const uint2*)(wc + 4);
                unsigned int w4 = *(const unsigned int*)(wc + 8);
                float f0, f1, f2, f3, f4, f5, f6, f7, f8, fd;
                up2(w01.x, f0, f1); up2(w01.y, f2, f3);
                up2(w23.x, f4, f5); up2(w23.y, f6, f7);
                up2(w4, f8, fd);
                acc[j] += f0*iv[0] + f1*iv[1] + f2*iv[2]
                        + f3*iv[3] + f4*iv[4] + f5*iv[5]
                        + f6*iv[6] + f7*iv[7] + f8*iv[8];
            }
        }
    }
    #pragma unroll
    for (int j = 0; j < 16; ++j) {
        int co = chalf * 32 + s * 16 + j;
        float qv = qt[n * 64 + co];
        size_t off = ((size_t)(n * 64 + co)) * HW + h * WB + w;
        t[off] = dct[off] + qv * (acc[j] + b1[co]);
    }
}

// ---------------- Encoder 1x1: x[n,h,w,e] = sum_ci t[n,ci,h,w]*w2[e,ci] + b2[e] ----------------
__global__ __launch_bounds__(128) void k_enc_proj(
    const float* __restrict__ t, const float* __restrict__ w2,
    const float* __restrict__ b2, float* __restrict__ x)
{
    int pos0 = blockIdx.x * 8;
    int n = pos0 >> 14;
    int rowoff = pos0 & 16383;
    __shared__ float tl[64 * 8];      // [ci][p]
    const float* tb = t + (size_t)n * CDCT * HW + rowoff;
    for (int k = 0; k < 4; ++k) {
        int idx = k * 128 + threadIdx.x;
        int ci = idx >> 3, p = idx & 7;
        tl[ci * 8 + p] = tb[(size_t)ci * HW + p];
    }
    __syncthreads();
    int o = threadIdx.x;
    float bias = b2[o];
    float acc[8];
    #pragma unroll
    for (int p = 0; p < 8; ++p) acc[p] = bias;
    for (int ci = 0; ci < 64; ++ci) {
        float wv = w2[o * 64 + ci];
        #pragma unroll
        for (int p = 0; p < 8; ++p) acc[p] += tl[ci * 8 + p] * wv;
    }
    float* xo = x + (size_t)pos0 * EE + o;
    #pragma unroll
    for (int p = 0; p < 8; ++p) xo[(size_t)p * EE] = acc[p];
}

// ============ LN1 + QKV via MFMA: 32 rows/block, 4 waves x 96 cols ============
__global__ __launch_bounds__(256) void k_qkv2(
    const float* __restrict__ x,
    const float* __restrict__ g, const float* __restrict__ b,
    const u16* __restrict__ wqkvt,
    const float* __restrict__ bq, const float* __restrict__ bk, const float* __restrict__ bv,
    u16* __restrict__ qo, u16* __restrict__ ko, u16* __restrict__ vo)
{
    int pos0 = blockIdx.x * 32;
    int tid = threadIdx.x;
    int lane = tid & 63, wv = tid >> 6;
    __shared__ u16 y0l[32][136];

    // LN1: thread = (row r = tid>>3, 16 cols at c0)
    {
        int r = tid >> 3, c0 = (tid & 7) * 16;
        const float* xr = x + (size_t)(pos0 + r) * EE + c0;
        float xv[16]; float s1 = 0.f, s2 = 0.f;
        #pragma unroll
        for (int i = 0; i < 16; ++i) { xv[i] = xr[i]; s1 += xv[i]; s2 += xv[i] * xv[i]; }
        #pragma unroll
        for (int off = 1; off < 8; off <<= 1) { s1 += __shfl_xor(s1, off); s2 += __shfl_xor(s2, off); }
        float m = s1 * (1.0f / 128.0f);
        float var = s2 * (1.0f / 128.0f) - m * m;
        float rstd = rsqrtf(var + EPSV);
        #pragma unroll
        for (int i = 0; i < 16; ++i)
            y0l[r][c0 + i] = f2bf((xv[i] - m) * rstd * g[c0 + i] + b[c0 + i]);
    }
    __syncthreads();

    // GEMM: A = y0l [32][128], B = wqkvt [384][128]; wave handles 6 n-tiles
    f32x4 acc[2][6];
    #pragma unroll
    for (int m = 0; m < 2; ++m)
        #pragma unroll
        for (int j = 0; j < 6; ++j) acc[m][j] = (f32x4){0.f, 0.f, 0.f, 0.f};
    int la = lane & 15, kb = (lane >> 4) << 3;
    #pragma unroll
    for (int kk = 0; kk < 4; ++kk) {
        s16x8 a0 = *(const s16x8*)&y0l[la][kk * 32 + kb];
        s16x8 a1 = *(const s16x8*)&y0l[16 + la][kk * 32 + kb];
        #pragma unroll
        for (int j = 0; j < 6; ++j) {
            int nt = wv * 6 + j;
            s16x8 bf = *(const s16x8*)(wqkvt + (size_t)(nt * 16 + la) * 128 + kk * 32 + kb);
            acc[0][j] = __builtin_amdgcn_mfma_f32_16x16x32_bf16(a0, bf, acc[0][j], 0, 0, 0);
            acc[1][j] = __builtin_amdgcn_mfma_f32_16x16x32_bf16(a1, bf, acc[1][j], 0, 0, 0);
        }
    }
    // epilogue
    #pragma unroll
    for (int j = 0; j < 6; ++j) {
        int nt = wv * 6 + j;
        int mat = nt >> 3;
        int ncol = (nt & 7) * 16 + la;
        float bias = (mat == 0) ? bq[ncol] : (mat == 1) ? bk[ncol] : bv[ncol];
        u16* dst = (mat == 0) ? qo : (mat == 1) ? ko : vo;
        #pragma unroll
        for (int m = 0; m < 2; ++m) {
            #pragma unroll
            for (int i = 0; i < 4; ++i) {
                int row = m * 16 + ((lane >> 4) << 2) + i;
                dst[(size_t)(pos0 + row) * EE + ncol] = f2bf(acc[m][j][i] + bias);
            }
        }
    }
}

// ---------------- 7x7 sliding-window attention (unchanged) ----------------
__global__ __launch_bounds__(256) void k_attn(
    const u16* __restrict__ q, const u16* __restrict__ k,
    const u16* __restrict__ v, const float* __restrict__ rb,
    float* __restrict__ y2)
{
    int pos0 = blockIdx.x * 64;
    int lane = threadIdx.x;      // 0..63
    int hd = threadIdx.y;        // 0..3
    int n = pos0 >> 14;
    int hrow = (pos0 & 16383) >> 7;
    int w = (pos0 & 127) + lane;
    __shared__ float rbl[NHD * PP];
    int tt = hd * 64 + lane;
    if (tt < NHD * PP) rbl[tt] = rb[tt];
    __syncthreads();
    const u16* qp = q + (size_t)(pos0 + lane) * EE + hd * 32;
    float qr[32];
    #pragma unroll
    for (int d4 = 0; d4 < 8; ++d4) {
        ushort4 u = *reinterpret_cast<const ushort4*>(qp + d4 * 4);
        qr[d4*4+0] = bf2f(u.x); qr[d4*4+1] = bf2f(u.y);
        qr[d4*4+2] = bf2f(u.z); qr[d4*4+3] = bf2f(u.w);
    }
    const float scale = 0.088388347648318447f; // 1/sqrt(128)
    float s[PP];
    float mx = -1e30f;
    #pragma unroll
    for (int di = 0; di < 7; ++di) {
        int hh = hrow + di - 3;
        #pragma unroll
        for (int dj = 0; dj < 7; ++dj) {
            int ww = w + dj - 3;
            int idx = di * 7 + dj;
            float sc = rbl[hd * PP + idx];
            if (hh >= 0 && hh < HB && ww >= 0 && ww < WB) {
                const u16* kp = k + ((size_t)n * HW + hh * WB + ww) * EE + hd * 32;
                float dot = 0.f;
                #pragma unroll
                for (int d4 = 0; d4 < 8; ++d4) {
                    ushort4 u = *reinterpret_cast<const ushort4*>(kp + d4 * 4);
                    dot += qr[d4*4+0]*bf2f(u.x) + qr[d4*4+1]*bf2f(u.y)
                         + qr[d4*4+2]*bf2f(u.z) + qr[d4*4+3]*bf2f(u.w);
                }
                sc += dot * scale;
            }
            s[idx] = sc;
            mx = fmaxf(mx, sc);
        }
    }
    float sum = 0.f;
    #pragma unroll
    for (int i = 0; i < PP; ++i) { float e_ = __expf(s[i] - mx); s[i] = e_; sum += e_; }
    float inv = 1.0f / sum;
    float acc[32];
    #pragma unroll
    for (int d = 0; d < 32; ++d) acc[d] = 0.f;
    #pragma unroll
    for (int di = 0; di < 7; ++di) {
        int hh = hrow + di - 3;
        if (hh < 0 || hh >= HB) continue;
        #pragma unroll
        for (int dj = 0; dj < 7; ++dj) {
            int ww = w + dj - 3;
            if (ww < 0 || ww >= WB) continue;
            float a = s[di * 7 + dj] * inv;
            const u16* vp = v + ((size_t)n * HW + hh * WB + ww) * EE + hd * 32;
            #pragma unroll
            for (int d4 = 0; d4 < 8; ++d4) {
                ushort4 u = *reinterpret_cast<const ushort4*>(vp + d4 * 4);
                acc[d4*4+0] += a * bf2f(u.x); acc[d4*4+1] += a * bf2f(u.y);
                acc[d4*4+2] += a * bf2f(u.z); acc[d4*4+3] += a * bf2f(u.w);
            }
        }
    }
    float* yo = y2 + (size_t)(pos0 + lane) * EE + hd * 32;
    #pragma unroll
    for (int d = 0; d < 32; ++d) yo[d] = acc[d];
}

// ============ LN2 + FF via MFMA + residual, x in place ============
// 32 rows/block, 4 waves. GEMM1: N=512 (128/wave); GEMM2: N=128 (32/wave).
__global__ __launch_bounds__(256) void k_ff2(
    float* __restrict__ x, const float* __restrict__ y2,
    const float* __restrict__ g, const float* __restrict__ b,
    const u16* __restrict__ w1t, const float* __restrict__ b1,
    const u16* __restrict__ w2t, const float* __restrict__ b2)
{
    int pos0 = blockIdx.x * 32;
    int tid = threadIdx.x;
    int lane = tid & 63, wv = tid >> 6;
    __shared__ u16 y3l[32][136];
    __shared__ u16 hl[32][520];

    // LN2 on tv = x + y2
    {
        int r = tid >> 3, c0 = (tid & 7) * 16;
        const float* xr = x + (size_t)(pos0 + r) * EE + c0;
        const float* yr = y2 + (size_t)(pos0 + r) * EE + c0;
        float tv[16]; float s1 = 0.f, s2 = 0.f;
        #pragma unroll
        for (int i = 0; i < 16; ++i) {
            tv[i] = xr[i] + yr[i];
            s1 += tv[i]; s2 += tv[i] * tv[i];
        }
        #pragma unroll
        for (int off = 1; off < 8; off <<= 1) { s1 += __shfl_xor(s1, off); s2 += __shfl_xor(s2, off); }
        float m = s1 * (1.0f / 128.0f);
        float var = s2 * (1.0f / 128.0f) - m * m;
        float rstd = rsqrtf(var + EPSV);
        #pragma unroll
        for (int i = 0; i < 16; ++i)
            y3l[r][c0 + i] = f2bf((tv[i] - m) * rstd * g[c0 + i] + b[c0 + i]);
    }
    __syncthreads();

    int la = lane & 15, kb = (lane >> 4) << 3;

    // GEMM1: [32x128] @ w1t^T -> h [32][512]; wave covers 128 N-cols
    {
        f32x4 acc[2][8];
        #pragma unroll
        for (int m = 0; m < 2; ++m)
            #pragma unroll
            for (int j = 0; j < 8; ++j) acc[m][j] = (f32x4){0.f, 0.f, 0.f, 0.f};
        int n0 = wv * 128;
        #pragma unroll
        for (int kk = 0; kk < 4; ++kk) {
            s16x8 a0 = *(const s16x8*)&y3l[la][kk * 32 + kb];
            s16x8 a1 = *(const s16x8*)&y3l[16 + la][kk * 32 + kb];
            #pragma unroll
            for (int j = 0; j < 8; ++j) {
                s16x8 bf = *(const s16x8*)(w1t + (size_t)(n0 + j * 16 + la) * 128 + kk * 32 + kb);
                acc[0][j] = __builtin_amdgcn_mfma_f32_16x16x32_bf16(a0, bf, acc[0][j], 0, 0, 0);
                acc[1][j] = __builtin_amdgcn_mfma_f32_16x16x32_bf16(a1, bf, acc[1][j], 0, 0, 0);
            }
        }
        // bias + exact gelu -> hl (bf16)
        #pragma unroll
        for (int j = 0; j < 8; ++j) {
            int col = n0 + j * 16 + la;
            float bb = b1[col];
            #pragma unroll
            for (int m = 0; m < 2; ++m) {
                #pragma unroll
                for (int i = 0; i < 4; ++i) {
                    int row = m * 16 + ((lane >> 4) << 2) + i;
                    float hx = acc[m][j][i] + bb;
                    float ge = 0.5f * hx * (1.0f + erff(hx * 0.70710678118654752f));
                    hl[row][col] = f2bf(ge);
                }
            }
        }
    }
    __syncthreads();

    // GEMM2: h [32][512] @ w2t^T -> [32][128]; wave covers 32 N-cols
    {
        f32x4 acc2[2][2];
        #pragma unroll
        for (int m = 0; m < 2; ++m)
            #pragma unroll
            for (int j = 0; j < 2; ++j) acc2[m][j] = (f32x4){0.f, 0.f, 0.f, 0.f};
        int n0 = wv * 32;
        #pragma unroll
        for (int kk = 0; kk < 16; ++kk) {
            s16x8 a0 = *(const s16x8*)&hl[la][kk * 32 + kb];
            s16x8 a1 = *(const s16x8*)&hl[16 + la][kk * 32 + kb];
            #pragma unroll
            for (int j = 0; j < 2; ++j) {
                s16x8 bf = *(const s16x8*)(w2t + (size_t)(n0 + j * 16 + la) * 512 + kk * 32 + kb);
                acc2[0][j] = __builtin_amdgcn_mfma_f32_16x16x32_bf16(a0, bf, acc2[0][j], 0, 0, 0);
                acc2[1][j] = __builtin_amdgcn_mfma_f32_16x16x32_bf16(a1, bf, acc2[1][j], 0, 0, 0);
            }
        }
        // out = y2(res) + acc2 + b2
        #pragma unroll
        for (int j = 0; j < 2; ++j) {
            int col = n0 + j * 16 + la;
            float bb = b2[col];
            #pragma unroll
            for (int m = 0; m < 2; ++m) {
                #pragma unroll
                for (int i = 0; i < 4; ++i) {
                    int row = m * 16 + ((lane >> 4) << 2) + i;
                    size_t grow = (size_t)(pos0 + row) * EE + col;
                    x[grow] = y2[grow] + acc2[m][j][i] + bb;
                }
            }
        }
    }
}

// ---------------- Decoder: out = dct + (x @ dec_w^T + dec_b) * qt ----------------
__global__ __launch_bounds__(256) void k_dec(
    const float* __restrict__ x, const float* __restrict__ dct,
    const float* __restrict__ qt, const float* __restrict__ wd,
    const float* __restrict__ bd, float* __restrict__ out)
{
    int pos0 = blockIdx.x * 64;
    int lane = threadIdx.x;
    int gq = threadIdx.y;
    int n = pos0 >> 14;
    int hw0 = pos0 & 16383;
    __shared__ float xl[64 * 129];
    for (int kk = 0; kk < 32; ++kk) {
        int idx = kk * 256 + gq * 64 + lane;
        int l = idx >> 7, e = idx & 127;
        xl[l * 129 + e] = x[(size_t)pos0 * EE + idx];
    }
    __syncthreads();
    for (int cc = 0; cc < 16; ++cc) {
        int co = gq * 16 + cc;
        float acc = 0.f;
        const float* wr = wd + co * 128;
        const float* xr = &xl[lane * 129];
        #pragma unroll
        for (int e4 = 0; e4 < 32; ++e4) {
            float4 u = *reinterpret_cast<const float4*>(wr + e4 * 4);
            acc += xr[e4*4+0]*u.x + xr[e4*4+1]*u.y
                 + xr[e4*4+2]*u.z + xr[e4*4+3]*u.w;
        }
        float qv = qt[n * CDCT + co];
        float r = (acc + bd[co]) * qv;
        size_t off = ((size_t)(n * CDCT + co)) * HW + hw0 + lane;
        out[off] = dct[off] + r;
    }
}

extern "C" void kernel_launch(void* const* d_in, const int* in_sizes, int n_in,
                              void* d_out, int out_size, void* d_ws, size_t ws_size,
                              hipStream_t stream) {
    const float* dct  = (const float*)d_in[0];
    const float* qt   = (const float*)d_in[1];
    const float* ec1w = (const float*)d_in[2];
    const float* ec1b = (const float*)d_in[3];
    const float* ec2w = (const float*)d_in[4];
    const float* ec2b = (const float*)d_in[5];
    const float* ln1g = (const float*)d_in[6];
    const float* ln1b = (const float*)d_in[7];
    const float* qw   = (const float*)d_in[8];
    const float* qb   = (const float*)d_in[9];
    const float* kw   = (const float*)d_in[10];
    const float* kb   = (const float*)d_in[11];
    const float* vw   = (const float*)d_in[12];
    const float* vb   = (const float*)d_in[13];
    const float* rb   = (const float*)d_in[14];
    const float* ln2g = (const float*)d_in[15];
    const float* ln2b = (const float*)d_in[16];
    const float* fw1  = (const float*)d_in[17];
    const float* fb1  = (const float*)d_in[18];
    const float* fw2  = (const float*)d_in[19];
    const float* fb2  = (const float*)d_in[20];
    const float* dw   = (const float*)d_in[21];
    const float* db   = (const float*)d_in[22];

    char* ws = (char*)d_ws;
    float* xbuf  = (float*)ws;                         // 67108864 B
    float* y2buf = (float*)(ws + 67108864);            // 67108864 B
    u16*   qbuf  = (u16*)(ws + 134217728);             // 33554432 B
    u16*   kbuf  = (u16*)(ws + 167772160);             // 33554432 B
    u16*   vbuf  = (u16*)(ws + 201326592);             // 33554432 B
    float* tbuf  = y2buf;                              // encoder temp
    size_t woff = 234881024;
    u16* wqkvt = (u16*)(ws + woff);                    // 393216 B
    u16* w1t   = (u16*)(ws + woff + 393216);           // 524288 B
    u16* w2t   = (u16*)(ws + woff + 917504);           // 524288 B
    u16* convw = (u16*)(ws + woff + 1441792);          // 98304 B

    k_prep_qkvff<<<dim3(2816), dim3(256), 0, stream>>>(qw, kw, vw, fw1, fw2, wqkvt, w1t, w2t);
    k_prep_conv<<<dim3(192), dim3(256), 0, stream>>>(ec1w, convw);

    k_enc_conv2<<<dim3(NB * HB * 2), dim3(256), 0, stream>>>(dct, qt, convw, ec1b, tbuf);
    k_enc_proj<<<dim3(NPOS / 8), dim3(128), 0, stream>>>(tbuf, ec2w, ec2b, xbuf);
    for (int l = 0; l < NLAY; ++l) {
        k_qkv2<<<dim3(NPOS / 32), dim3(256), 0, stream>>>(
            xbuf, ln1g + l * EE, ln1b + l * EE,
            wqkvt + l * 49152,
            qb + l * EE, kb + l * EE, vb + l * EE,
            qbuf, kbuf, vbuf);
        k_attn<<<dim3(NPOS / 64), dim3(64, 4), 0, stream>>>(
            qbuf, kbuf, vbuf, rb + l * NHD * PP, y2buf);
        k_ff2<<<dim3(NPOS / 32), dim3(256), 0, stream>>>(
            xbuf, y2buf, ln2g + l * EE, ln2b + l * EE,
            w1t + l * 65536, fb1 + l * DFF,
            w2t + l * 65536, fb2 + l * EE);
    }
    k_dec<<<dim3(NPOS / 64), dim3(64, 4), 0, stream>>>(
        xbuf, dct, qt, dw, db, (float*)d_out);
}

// Round 5
// 2060.580 us; speedup vs baseline: 3.6751x; 1.8510x over previous
//
#include <hip/hip_runtime.h>
#include <math.h>

#define NB 8
#define CDCT 64
#define HB 128
#define WB 128
#define EE 128
#define NHD 4
#define KS 7
#define PP 49
#define DFF 512
#define NLAY 4
#define HW (HB*WB)          // 16384
#define NPOS (NB*HB*WB)     // 131072
#define EPSV 1e-5f

typedef unsigned short u16;
typedef float f32x4 __attribute__((ext_vector_type(4)));
typedef short s16x8 __attribute__((ext_vector_type(8)));

__device__ __forceinline__ float bf2f(u16 u) {
    union { unsigned int i; float f; } c; c.i = ((unsigned int)u) << 16; return c.f;
}
__device__ __forceinline__ u16 f2bf(float f) {
    union { float f; unsigned int i; } c; c.f = f;
    unsigned int x = c.i;
    return (u16)((x + 0x7fffu + ((x >> 16) & 1u)) >> 16);
}

// ============ prep: transpose+convert transformer weights to bf16 ============
__global__ __launch_bounds__(256) void k_prep_qkvff(
    const float* __restrict__ qw, const float* __restrict__ kw, const float* __restrict__ vw,
    const float* __restrict__ fw1, const float* __restrict__ fw2,
    u16* __restrict__ wqkvt, u16* __restrict__ w1t, u16* __restrict__ w2t)
{
    int idx = blockIdx.x * 256 + threadIdx.x;      // < 720896
    int l = idx / 180224;
    int rem = idx - l * 180224;
    if (rem < 49152) {
        int n = rem >> 7, k2 = rem & 127;
        int mat = n >> 7, c = n & 127;
        const float* src = (mat == 0) ? qw : (mat == 1) ? kw : vw;
        wqkvt[l * 49152 + rem] = f2bf(src[l * 16384 + k2 * 128 + c]);
    } else if (rem < 114688) {
        int r2 = rem - 49152;
        int j = r2 >> 7, i = r2 & 127;
        w1t[l * 65536 + r2] = f2bf(fw1[l * 65536 + i * 512 + j]);
    } else {
        int r3 = rem - 114688;
        int e = r3 >> 9, d = r3 & 511;
        w2t[l * 65536 + r3] = f2bf(fw2[l * 65536 + d * 128 + e]);
    }
}

// prep conv weights: wtap[tap(9)][co(64)][ci(64)] bf16
__global__ __launch_bounds__(256) void k_prep_conv(
    const float* __restrict__ ec1w, u16* __restrict__ wtap)
{
    int idx = blockIdx.x * 256 + threadIdx.x;      // < 36864
    int tap = idx >> 12;
    int r = idx & 4095;
    int co = r >> 6, ci = r & 63;
    wtap[idx] = f2bf(ec1w[co * 576 + ci * 9 + tap]);
}

// ============ Encoder conv 3x3 via shifted MFMA GEMM + FiLM ============
// block = (n,h): 128 w-positions x 64 co. 256 threads = 4 waves, wave = 32 w.
__global__ __launch_bounds__(256) void k_enc_conv3(
    const float* __restrict__ dct, const float* __restrict__ qt,
    const u16* __restrict__ wtap, const float* __restrict__ b1,
    float* __restrict__ t)
{
    int h = blockIdx.x & 127, n = blockIdx.x >> 7;
    int tid = threadIdx.x;
    int lane = tid & 63, wv = tid >> 6;
    int la = lane & 15, hi = lane >> 4, kb8 = hi * 8;
    __shared__ u16 inl[3][132][72];   // wi = w+1 (w=-1..130), ci padded 64->72; 57024 B

    // zero edge columns wi=0 (w=-1) and wi=129 (w=128)
    for (int e = tid; e < 384; e += 256) {
        int dh = e >> 7, r = e & 127;
        int ci = r >> 1, wi = (r & 1) * 129;
        inl[dh][wi][ci] = 0;
    }
    // main staging: 3 rows x 64 ci x 128 w
    #pragma unroll
    for (int dh = 0; dh < 3; ++dh) {
        int hh = h + dh - 1;
        bool ok = (hh >= 0) && (hh < HB);
        for (int it = 0; it < 32; ++it) {
            int e = it * 256 + tid;
            int ci = e >> 7, w = e & 127;
            float v = ok ? dct[((size_t)(n * 64 + ci) * HW) + hh * WB + w] : 0.f;
            inl[dh][w + 1][ci] = f2bf(v);
        }
    }
    __syncthreads();

    f32x4 acc[2][4];
    #pragma unroll
    for (int m = 0; m < 2; ++m)
        #pragma unroll
        for (int nt = 0; nt < 4; ++nt) acc[m][nt] = (f32x4){0.f, 0.f, 0.f, 0.f};

    #pragma unroll
    for (int dh = 0; dh < 3; ++dh) {
        #pragma unroll
        for (int dw = 0; dw < 3; ++dw) {
            #pragma unroll
            for (int kk = 0; kk < 2; ++kk) {
                s16x8 a0 = *(const s16x8*)&inl[dh][wv * 32 + la + dw][kk * 32 + kb8];
                s16x8 a1 = *(const s16x8*)&inl[dh][wv * 32 + 16 + la + dw][kk * 32 + kb8];
                const u16* wb = wtap + (dh * 3 + dw) * 4096 + kk * 32 + kb8;
                #pragma unroll
                for (int nt = 0; nt < 4; ++nt) {
                    s16x8 bf = *(const s16x8*)(wb + (nt * 16 + la) * 64);
                    acc[0][nt] = __builtin_amdgcn_mfma_f32_16x16x32_bf16(a0, bf, acc[0][nt], 0, 0, 0);
                    acc[1][nt] = __builtin_amdgcn_mfma_f32_16x16x32_bf16(a1, bf, acc[1][nt], 0, 0, 0);
                }
            }
        }
    }
    // epilogue: t = dct + qt*(acc + b1); float4 over 4 consecutive w
    #pragma unroll
    for (int mt = 0; mt < 2; ++mt) {
        #pragma unroll
        for (int nt = 0; nt < 4; ++nt) {
            int co = nt * 16 + la;
            int w0 = wv * 32 + mt * 16 + hi * 4;
            float qv = qt[n * 64 + co];
            float bb = b1[co];
            size_t off = ((size_t)(n * 64 + co) * HW) + h * WB + w0;
            float4 d4 = *reinterpret_cast<const float4*>(dct + off);
            float4 r;
            r.x = d4.x + qv * (acc[mt][nt][0] + bb);
            r.y = d4.y + qv * (acc[mt][nt][1] + bb);
            r.z = d4.z + qv * (acc[mt][nt][2] + bb);
            r.w = d4.w + qv * (acc[mt][nt][3] + bb);
            *reinterpret_cast<float4*>(t + off) = r;
        }
    }
}

// ---------------- Encoder 1x1 ----------------
__global__ __launch_bounds__(128) void k_enc_proj(
    const float* __restrict__ t, const float* __restrict__ w2,
    const float* __restrict__ b2, float* __restrict__ x)
{
    int pos0 = blockIdx.x * 8;
    int n = pos0 >> 14;
    int rowoff = pos0 & 16383;
    __shared__ float tl[64 * 8];
    const float* tb = t + (size_t)n * CDCT * HW + rowoff;
    for (int k = 0; k < 4; ++k) {
        int idx = k * 128 + threadIdx.x;
        int ci = idx >> 3, p = idx & 7;
        tl[ci * 8 + p] = tb[(size_t)ci * HW + p];
    }
    __syncthreads();
    int o = threadIdx.x;
    float bias = b2[o];
    float acc[8];
    #pragma unroll
    for (int p = 0; p < 8; ++p) acc[p] = bias;
    for (int ci = 0; ci < 64; ++ci) {
        float wv = w2[o * 64 + ci];
        #pragma unroll
        for (int p = 0; p < 8; ++p) acc[p] += tl[ci * 8 + p] * wv;
    }
    float* xo = x + (size_t)pos0 * EE + o;
    #pragma unroll
    for (int p = 0; p < 8; ++p) xo[(size_t)p * EE] = acc[p];
}

// ============ LN1 + QKV via MFMA ============
__global__ __launch_bounds__(256) void k_qkv2(
    const float* __restrict__ x,
    const float* __restrict__ g, const float* __restrict__ b,
    const u16* __restrict__ wqkvt,
    const float* __restrict__ bq, const float* __restrict__ bk, const float* __restrict__ bv,
    u16* __restrict__ qo, u16* __restrict__ ko, u16* __restrict__ vo)
{
    int pos0 = blockIdx.x * 32;
    int tid = threadIdx.x;
    int lane = tid & 63, wv = tid >> 6;
    __shared__ u16 y0l[32][136];

    {
        int r = tid >> 3, c0 = (tid & 7) * 16;
        const float* xr = x + (size_t)(pos0 + r) * EE + c0;
        float xv[16]; float s1 = 0.f, s2 = 0.f;
        #pragma unroll
        for (int i = 0; i < 16; ++i) { xv[i] = xr[i]; s1 += xv[i]; s2 += xv[i] * xv[i]; }
        #pragma unroll
        for (int off = 1; off < 8; off <<= 1) { s1 += __shfl_xor(s1, off); s2 += __shfl_xor(s2, off); }
        float m = s1 * (1.0f / 128.0f);
        float var = s2 * (1.0f / 128.0f) - m * m;
        float rstd = rsqrtf(var + EPSV);
        #pragma unroll
        for (int i = 0; i < 16; ++i)
            y0l[r][c0 + i] = f2bf((xv[i] - m) * rstd * g[c0 + i] + b[c0 + i]);
    }
    __syncthreads();

    f32x4 acc[2][6];
    #pragma unroll
    for (int m = 0; m < 2; ++m)
        #pragma unroll
        for (int j = 0; j < 6; ++j) acc[m][j] = (f32x4){0.f, 0.f, 0.f, 0.f};
    int la = lane & 15, kb = (lane >> 4) << 3;
    #pragma unroll
    for (int kk = 0; kk < 4; ++kk) {
        s16x8 a0 = *(const s16x8*)&y0l[la][kk * 32 + kb];
        s16x8 a1 = *(const s16x8*)&y0l[16 + la][kk * 32 + kb];
        #pragma unroll
        for (int j = 0; j < 6; ++j) {
            int nt = wv * 6 + j;
            s16x8 bf = *(const s16x8*)(wqkvt + (size_t)(nt * 16 + la) * 128 + kk * 32 + kb);
            acc[0][j] = __builtin_amdgcn_mfma_f32_16x16x32_bf16(a0, bf, acc[0][j], 0, 0, 0);
            acc[1][j] = __builtin_amdgcn_mfma_f32_16x16x32_bf16(a1, bf, acc[1][j], 0, 0, 0);
        }
    }
    #pragma unroll
    for (int j = 0; j < 6; ++j) {
        int nt = wv * 6 + j;
        int mat = nt >> 3;
        int ncol = (nt & 7) * 16 + la;
        float bias = (mat == 0) ? bq[ncol] : (mat == 1) ? bk[ncol] : bv[ncol];
        u16* dst = (mat == 0) ? qo : (mat == 1) ? ko : vo;
        #pragma unroll
        for (int m = 0; m < 2; ++m) {
            #pragma unroll
            for (int i = 0; i < 4; ++i) {
                int row = m * 16 + ((lane >> 4) << 2) + i;
                dst[(size_t)(pos0 + row) * EE + ncol] = f2bf(acc[m][j][i] + bias);
            }
        }
    }
}

// ============ 7x7 sliding-window attention via masked MFMA ============
// block = (n, 4-row group h0, 16-col group w0, head). 256 thr = 4 waves; wave = q row h0+wv.
__global__ __launch_bounds__(256) void k_attn2(
    const u16* __restrict__ q, const u16* __restrict__ k,
    const u16* __restrict__ v, const float* __restrict__ rb,
    float* __restrict__ y2)
{
    int bid = blockIdx.x;
    int hd = bid & 3;
    int wg = (bid >> 2) & 7;
    int hg = (bid >> 5) & 31;
    int n = bid >> 10;
    int h0 = hg * 4, w0 = wg * 16;
    int tid = threadIdx.x;
    int lane = tid & 63, wv = tid >> 6;
    int la = lane & 15, hi = lane >> 4, kb8 = hi * 8;

    __shared__ u16 ksl[224][40];    // [kpos][dim pad 40] 17920 B
    __shared__ u16 vtl[32][232];    // [dim][kpos pad 232] 14848 B
    __shared__ u16 psl[64][232];    // [q][kpos pad 232]   29696 B
    __shared__ float rbl[PP];

    if (tid < PP) rbl[tid] = rb[hd * PP + tid];

    // stage K and V^T (zero-padded outside image / beyond kpos 219)
    for (int c = tid; c < 896; c += 256) {
        int kpos = c >> 2, qtr = c & 3;
        int kr = kpos / 22, kc = kpos - kr * 22;
        int hh = h0 + kr - 3, ww = w0 + kc - 3;
        s16x8 kvv = (s16x8){0,0,0,0,0,0,0,0};
        s16x8 vvv = (s16x8){0,0,0,0,0,0,0,0};
        if (kpos < 220 && hh >= 0 && hh < HB && ww >= 0 && ww < WB) {
            size_t base = ((size_t)(n * HW + hh * WB + ww)) * EE + hd * 32 + qtr * 8;
            kvv = *(const s16x8*)(k + base);
            vvv = *(const s16x8*)(v + base);
        }
        *(s16x8*)&ksl[kpos][qtr * 8] = kvv;
        #pragma unroll
        for (int d = 0; d < 8; ++d) vtl[qtr * 8 + d][kpos] = (u16)vvv[d];
    }
    __syncthreads();

    // Q fragment: wave's q row = h0+wv, 16 cols w0..w0+15
    s16x8 qf = *(const s16x8*)(q + ((size_t)(n * HW + (h0 + wv) * WB + w0 + la)) * EE + hd * 32 + kb8);

    // S = Q.K^T over 224-padded window: 14 n-tiles, K=32
    f32x4 s[14];
    #pragma unroll
    for (int j = 0; j < 14; ++j) s[j] = (f32x4){0.f, 0.f, 0.f, 0.f};
    #pragma unroll
    for (int j = 0; j < 14; ++j) {
        s16x8 bf = *(const s16x8*)&ksl[j * 16 + la][kb8];
        s[j] = __builtin_amdgcn_mfma_f32_16x16x32_bf16(qf, bf, s[j], 0, 0, 0);
    }

    // scale + rel_bias + window mask
    const float scale = 0.088388347648318447f; // 1/sqrt(128)
    #pragma unroll
    for (int j = 0; j < 14; ++j) {
        int kpos = j * 16 + la;
        int kr = kpos / 22, kc = kpos - kr * 22;
        int di = kr - wv;
        bool rowok = (kpos < 220) && (di >= 0) && (di <= 6);
        #pragma unroll
        for (int i = 0; i < 4; ++i) {
            int qc = hi * 4 + i;
            int dj = kc - qc;
            bool ok = rowok && (dj >= 0) && (dj <= 6);
            s[j][i] = ok ? (s[j][i] * scale + rbl[di * 7 + dj]) : -1e30f;
        }
    }
    // softmax per q row (scores spread over 16-lane group, 14 regs)
    float mx[4] = {-1e30f, -1e30f, -1e30f, -1e30f};
    #pragma unroll
    for (int j = 0; j < 14; ++j)
        #pragma unroll
        for (int i = 0; i < 4; ++i) mx[i] = fmaxf(mx[i], s[j][i]);
    #pragma unroll
    for (int off = 1; off < 16; off <<= 1)
        #pragma unroll
        for (int i = 0; i < 4; ++i) mx[i] = fmaxf(mx[i], __shfl_xor(mx[i], off));
    float sum[4] = {0.f, 0.f, 0.f, 0.f};
    #pragma unroll
    for (int j = 0; j < 14; ++j)
        #pragma unroll
        for (int i = 0; i < 4; ++i) {
            float e_ = __expf(s[j][i] - mx[i]);
            s[j][i] = e_; sum[i] += e_;
        }
    #pragma unroll
    for (int off = 1; off < 16; off <<= 1)
        #pragma unroll
        for (int i = 0; i < 4; ++i) sum[i] += __shfl_xor(sum[i], off);
    float inv[4];
    #pragma unroll
    for (int i = 0; i < 4; ++i) inv[i] = 1.0f / sum[i];
    // P -> LDS bf16
    #pragma unroll
    for (int j = 0; j < 14; ++j)
        #pragma unroll
        for (int i = 0; i < 4; ++i)
            psl[wv * 16 + hi * 4 + i][j * 16 + la] = f2bf(s[j][i] * inv[i]);

    // PV: M=16 (wave q rows), N=32, K=224 — within-wave LDS dependency only
    f32x4 o[2];
    o[0] = (f32x4){0.f, 0.f, 0.f, 0.f};
    o[1] = (f32x4){0.f, 0.f, 0.f, 0.f};
    #pragma unroll
    for (int kk = 0; kk < 7; ++kk) {
        s16x8 pa = *(const s16x8*)&psl[wv * 16 + la][kk * 32 + kb8];
        #pragma unroll
        for (int nt = 0; nt < 2; ++nt) {
            s16x8 vb = *(const s16x8*)&vtl[nt * 16 + la][kk * 32 + kb8];
            o[nt] = __builtin_amdgcn_mfma_f32_16x16x32_bf16(pa, vb, o[nt], 0, 0, 0);
        }
    }
    #pragma unroll
    for (int nt = 0; nt < 2; ++nt) {
        #pragma unroll
        for (int i = 0; i < 4; ++i) {
            int qc = hi * 4 + i;
            y2[((size_t)(n * HW + (h0 + wv) * WB + w0 + qc)) * EE + hd * 32 + nt * 16 + la] = o[nt][i];
        }
    }
}

// ============ LN2 + FF via MFMA + residual ============
__global__ __launch_bounds__(256) void k_ff2(
    float* __restrict__ x, const float* __restrict__ y2,
    const float* __restrict__ g, const float* __restrict__ b,
    const u16* __restrict__ w1t, const float* __restrict__ b1,
    const u16* __restrict__ w2t, const float* __restrict__ b2)
{
    int pos0 = blockIdx.x * 32;
    int tid = threadIdx.x;
    int lane = tid & 63, wv = tid >> 6;
    __shared__ u16 y3l[32][136];
    __shared__ u16 hl[32][520];

    {
        int r = tid >> 3, c0 = (tid & 7) * 16;
        const float* xr = x + (size_t)(pos0 + r) * EE + c0;
        const float* yr = y2 + (size_t)(pos0 + r) * EE + c0;
        float tv[16]; float s1 = 0.f, s2 = 0.f;
        #pragma unroll
        for (int i = 0; i < 16; ++i) {
            tv[i] = xr[i] + yr[i];
            s1 += tv[i]; s2 += tv[i] * tv[i];
        }
        #pragma unroll
        for (int off = 1; off < 8; off <<= 1) { s1 += __shfl_xor(s1, off); s2 += __shfl_xor(s2, off); }
        float m = s1 * (1.0f / 128.0f);
        float var = s2 * (1.0f / 128.0f) - m * m;
        float rstd = rsqrtf(var + EPSV);
        #pragma unroll
        for (int i = 0; i < 16; ++i)
            y3l[r][c0 + i] = f2bf((tv[i] - m) * rstd * g[c0 + i] + b[c0 + i]);
    }
    __syncthreads();

    int la = lane & 15, kb = (lane >> 4) << 3;

    {
        f32x4 acc[2][8];
        #pragma unroll
        for (int m = 0; m < 2; ++m)
            #pragma unroll
            for (int j = 0; j < 8; ++j) acc[m][j] = (f32x4){0.f, 0.f, 0.f, 0.f};
        int n0 = wv * 128;
        #pragma unroll
        for (int kk = 0; kk < 4; ++kk) {
            s16x8 a0 = *(const s16x8*)&y3l[la][kk * 32 + kb];
            s16x8 a1 = *(const s16x8*)&y3l[16 + la][kk * 32 + kb];
            #pragma unroll
            for (int j = 0; j < 8; ++j) {
                s16x8 bf = *(const s16x8*)(w1t + (size_t)(n0 + j * 16 + la) * 128 + kk * 32 + kb);
                acc[0][j] = __builtin_amdgcn_mfma_f32_16x16x32_bf16(a0, bf, acc[0][j], 0, 0, 0);
                acc[1][j] = __builtin_amdgcn_mfma_f32_16x16x32_bf16(a1, bf, acc[1][j], 0, 0, 0);
            }
        }
        #pragma unroll
        for (int j = 0; j < 8; ++j) {
            int col = n0 + j * 16 + la;
            float bb = b1[col];
            #pragma unroll
            for (int m = 0; m < 2; ++m) {
                #pragma unroll
                for (int i = 0; i < 4; ++i) {
                    int row = m * 16 + ((lane >> 4) << 2) + i;
                    float hx = acc[m][j][i] + bb;
                    float ge = 0.5f * hx * (1.0f + erff(hx * 0.70710678118654752f));
                    hl[row][col] = f2bf(ge);
                }
            }
        }
    }
    __syncthreads();

    {
        f32x4 acc2[2][2];
        #pragma unroll
        for (int m = 0; m < 2; ++m)
            #pragma unroll
            for (int j = 0; j < 2; ++j) acc2[m][j] = (f32x4){0.f, 0.f, 0.f, 0.f};
        int n0 = wv * 32;
        #pragma unroll
        for (int kk = 0; kk < 16; ++kk) {
            s16x8 a0 = *(const s16x8*)&hl[la][kk * 32 + kb];
            s16x8 a1 = *(const s16x8*)&hl[16 + la][kk * 32 + kb];
            #pragma unroll
            for (int j = 0; j < 2; ++j) {
                s16x8 bf = *(const s16x8*)(w2t + (size_t)(n0 + j * 16 + la) * 512 + kk * 32 + kb);
                acc2[0][j] = __builtin_amdgcn_mfma_f32_16x16x32_bf16(a0, bf, acc2[0][j], 0, 0, 0);
                acc2[1][j] = __builtin_amdgcn_mfma_f32_16x16x32_bf16(a1, bf, acc2[1][j], 0, 0, 0);
            }
        }
        #pragma unroll
        for (int j = 0; j < 2; ++j) {
            int col = n0 + j * 16 + la;
            float bb = b2[col];
            #pragma unroll
            for (int m = 0; m < 2; ++m) {
                #pragma unroll
                for (int i = 0; i < 4; ++i) {
                    int row = m * 16 + ((lane >> 4) << 2) + i;
                    size_t grow = (size_t)(pos0 + row) * EE + col;
                    x[grow] = y2[grow] + acc2[m][j][i] + bb;
                }
            }
        }
    }
}

// ---------------- Decoder ----------------
__global__ __launch_bounds__(256) void k_dec(
    const float* __restrict__ x, const float* __restrict__ dct,
    const float* __restrict__ qt, const float* __restrict__ wd,
    const float* __restrict__ bd, float* __restrict__ out)
{
    int pos0 = blockIdx.x * 64;
    int lane = threadIdx.x;
    int gq = threadIdx.y;
    int n = pos0 >> 14;
    int hw0 = pos0 & 16383;
    __shared__ float xl[64 * 129];
    for (int kk = 0; kk < 32; ++kk) {
        int idx = kk * 256 + gq * 64 + lane;
        int l = idx >> 7, e = idx & 127;
        xl[l * 129 + e] = x[(size_t)pos0 * EE + idx];
    }
    __syncthreads();
    for (int cc = 0; cc < 16; ++cc) {
        int co = gq * 16 + cc;
        float acc = 0.f;
        const float* wr = wd + co * 128;
        const float* xr = &xl[lane * 129];
        #pragma unroll
        for (int e4 = 0; e4 < 32; ++e4) {
            float4 u = *reinterpret_cast<const float4*>(wr + e4 * 4);
            acc += xr[e4*4+0]*u.x + xr[e4*4+1]*u.y
                 + xr[e4*4+2]*u.z + xr[e4*4+3]*u.w;
        }
        float qv = qt[n * CDCT + co];
        float r = (acc + bd[co]) * qv;
        size_t off = ((size_t)(n * CDCT + co)) * HW + hw0 + lane;
        out[off] = dct[off] + r;
    }
}

extern "C" void kernel_launch(void* const* d_in, const int* in_sizes, int n_in,
                              void* d_out, int out_size, void* d_ws, size_t ws_size,
                              hipStream_t stream) {
    const float* dct  = (const float*)d_in[0];
    const float* qt   = (const float*)d_in[1];
    const float* ec1w = (const float*)d_in[2];
    const float* ec1b = (const float*)d_in[3];
    const float* ec2w = (const float*)d_in[4];
    const float* ec2b = (const float*)d_in[5];
    const float* ln1g = (const float*)d_in[6];
    const float* ln1b = (const float*)d_in[7];
    const float* qw   = (const float*)d_in[8];
    const float* qb   = (const float*)d_in[9];
    const float* kw   = (const float*)d_in[10];
    const float* kb   = (const float*)d_in[11];
    const float* vw   = (const float*)d_in[12];
    const float* vb   = (const float*)d_in[13];
    const float* rb   = (const float*)d_in[14];
    const float* ln2g = (const float*)d_in[15];
    const float* ln2b = (const float*)d_in[16];
    const float* fw1  = (const float*)d_in[17];
    const float* fb1  = (const float*)d_in[18];
    const float* fw2  = (const float*)d_in[19];
    const float* fb2  = (const float*)d_in[20];
    const float* dw   = (const float*)d_in[21];
    const float* db   = (const float*)d_in[22];

    char* ws = (char*)d_ws;
    float* xbuf  = (float*)ws;                         // 67108864 B
    float* y2buf = (float*)(ws + 67108864);            // 67108864 B
    u16*   qbuf  = (u16*)(ws + 134217728);             // 33554432 B
    u16*   kbuf  = (u16*)(ws + 167772160);             // 33554432 B
    u16*   vbuf  = (u16*)(ws + 201326592);             // 33554432 B
    float* tbuf  = y2buf;                              // encoder temp
    size_t woff = 234881024;
    u16* wqkvt = (u16*)(ws + woff);                    // 393216 B
    u16* w1t   = (u16*)(ws + woff + 393216);           // 524288 B
    u16* w2t   = (u16*)(ws + woff + 917504);           // 524288 B
    u16* wtap  = (u16*)(ws + woff + 1441792);          // 73728 B

    k_prep_qkvff<<<dim3(2816), dim3(256), 0, stream>>>(qw, kw, vw, fw1, fw2, wqkvt, w1t, w2t);
    k_prep_conv<<<dim3(144), dim3(256), 0, stream>>>(ec1w, wtap);

    k_enc_conv3<<<dim3(NB * HB), dim3(256), 0, stream>>>(dct, qt, wtap, ec1b, tbuf);
    k_enc_proj<<<dim3(NPOS / 8), dim3(128), 0, stream>>>(tbuf, ec2w, ec2b, xbuf);
    for (int l = 0; l < NLAY; ++l) {
        k_qkv2<<<dim3(NPOS / 32), dim3(256), 0, stream>>>(
            xbuf, ln1g + l * EE, ln1b + l * EE,
            wqkvt + l * 49152,
            qb + l * EE, kb + l * EE, vb + l * EE,
            qbuf, kbuf, vbuf);
        k_attn2<<<dim3(NB * 32 * 8 * 4), dim3(256), 0, stream>>>(
            qbuf, kbuf, vbuf, rb + l * NHD * PP, y2buf);
        k_ff2<<<dim3(NPOS / 32), dim3(256), 0, stream>>>(
            xbuf, y2buf, ln2g + l * EE, ln2b + l * EE,
            w1t + l * 65536, fb1 + l * DFF,
            w2t + l * 65536, fb2 + l * EE);
    }
    k_dec<<<dim3(NPOS / 64), dim3(64, 4), 0, stream>>>(
        xbuf, dct, qt, dw, db, (float*)d_out);
}

// Round 6
// 1697.668 us; speedup vs baseline: 4.4608x; 1.2138x over previous
//
#include <hip/hip_runtime.h>
#include <math.h>

#define NB 8
#define CDCT 64
#define HB 128
#define WB 128
#define EE 128
#define NHD 4
#define KS 7
#define PP 49
#define DFF 512
#define NLAY 4
#define HW (HB*WB)          // 16384
#define NPOS (NB*HB*WB)     // 131072
#define EPSV 1e-5f

typedef unsigned short u16;
typedef float f32x4 __attribute__((ext_vector_type(4)));
typedef short s16x8 __attribute__((ext_vector_type(8)));

__device__ __forceinline__ float bf2f(u16 u) {
    union { unsigned int i; float f; } c; c.i = ((unsigned int)u) << 16; return c.f;
}
__device__ __forceinline__ u16 f2bf(float f) {
    union { float f; unsigned int i; } c; c.f = f;
    unsigned int x = c.i;
    return (u16)((x + 0x7fffu + ((x >> 16) & 1u)) >> 16);
}
// GELU: exact sigmoid form of the tanh approximation (<=0.003 abs dev from erf-GELU,
// below bf16 rounding of h). 1 exp + 1 div instead of erff's ~25-30 VALU ops.
__device__ __forceinline__ float gelu_f(float x) {
    float t2 = 1.5957691216057308f * (x + 0.044715f * x * x * x);
    return x / (1.0f + __expf(-t2));
}

// ============ prep: transpose+convert transformer weights to bf16 ============
__global__ __launch_bounds__(256) void k_prep_qkvff(
    const float* __restrict__ qw, const float* __restrict__ kw, const float* __restrict__ vw,
    const float* __restrict__ fw1, const float* __restrict__ fw2,
    u16* __restrict__ wqkvt, u16* __restrict__ w1t, u16* __restrict__ w2t)
{
    int idx = blockIdx.x * 256 + threadIdx.x;      // < 720896
    int l = idx / 180224;
    int rem = idx - l * 180224;
    if (rem < 49152) {
        int n = rem >> 7, k2 = rem & 127;
        int mat = n >> 7, c = n & 127;
        const float* src = (mat == 0) ? qw : (mat == 1) ? kw : vw;
        wqkvt[l * 49152 + rem] = f2bf(src[l * 16384 + k2 * 128 + c]);
    } else if (rem < 114688) {
        int r2 = rem - 49152;
        int j = r2 >> 7, i = r2 & 127;
        w1t[l * 65536 + r2] = f2bf(fw1[l * 65536 + i * 512 + j]);
    } else {
        int r3 = rem - 114688;
        int e = r3 >> 9, d = r3 & 511;
        w2t[l * 65536 + r3] = f2bf(fw2[l * 65536 + d * 128 + e]);
    }
}

// prep conv/enc-proj/decoder weights: wtap[tap(9)][co(64)][ci(64)], w2b[e][ci], dwb[co][e]
__global__ __launch_bounds__(256) void k_prep_conv(
    const float* __restrict__ ec1w, const float* __restrict__ ec2w,
    const float* __restrict__ dw,
    u16* __restrict__ wtap, u16* __restrict__ w2b, u16* __restrict__ dwb)
{
    int idx = blockIdx.x * 256 + threadIdx.x;      // < 53248
    if (idx < 36864) {
        int tap = idx >> 12;
        int r = idx & 4095;
        int co = r >> 6, ci = r & 63;
        wtap[idx] = f2bf(ec1w[co * 576 + ci * 9 + tap]);
    } else if (idx < 45056) {
        int r = idx - 36864;
        w2b[r] = f2bf(ec2w[r]);
    } else if (idx < 53248) {
        int r = idx - 45056;
        dwb[r] = f2bf(dw[r]);
    }
}

// ============ Encoder conv 3x3 via shifted MFMA + FiLM + fused 1x1 proj ============
// block = (n,h): 128 w x 64 co conv, then x[pos][e] = FiLM-tile @ w2b + b2.
__global__ __launch_bounds__(256) void k_enc_conv3(
    const float* __restrict__ dct, const float* __restrict__ qt,
    const u16* __restrict__ wtap, const float* __restrict__ b1,
    const u16* __restrict__ w2b, const float* __restrict__ eb2,
    float* __restrict__ x)
{
    int h = blockIdx.x & 127, n = blockIdx.x >> 7;
    int tid = threadIdx.x;
    int lane = tid & 63, wv = tid >> 6;
    int la = lane & 15, hi = lane >> 4, kb8 = hi * 8;
    __shared__ u16 smem[3 * 132 * 72];   // 57024 B; conv input, then reused as FiLM tile
    u16 (*inl)[132][72] = reinterpret_cast<u16 (*)[132][72]>(smem);
    u16 (*tl)[72] = reinterpret_cast<u16 (*)[72]>(smem);   // [w(128)][ci(64) pad 72]

    // zero edge columns wi=0 (w=-1) and wi=129 (w=128)
    for (int e = tid; e < 384; e += 256) {
        int dh = e >> 7, r = e & 127;
        int ci = r >> 1, wi = (r & 1) * 129;
        inl[dh][wi][ci] = 0;
    }
    // main staging: 3 rows x 64 ci x 128 w
    #pragma unroll
    for (int dh = 0; dh < 3; ++dh) {
        int hh = h + dh - 1;
        bool ok = (hh >= 0) && (hh < HB);
        for (int it = 0; it < 32; ++it) {
            int e = it * 256 + tid;
            int ci = e >> 7, w = e & 127;
            float v = ok ? dct[((size_t)(n * 64 + ci) * HW) + hh * WB + w] : 0.f;
            inl[dh][w + 1][ci] = f2bf(v);
        }
    }
    __syncthreads();

    f32x4 acc[2][4];
    #pragma unroll
    for (int m = 0; m < 2; ++m)
        #pragma unroll
        for (int nt = 0; nt < 4; ++nt) acc[m][nt] = (f32x4){0.f, 0.f, 0.f, 0.f};

    #pragma unroll
    for (int dh = 0; dh < 3; ++dh) {
        #pragma unroll
        for (int dw = 0; dw < 3; ++dw) {
            #pragma unroll
            for (int kk = 0; kk < 2; ++kk) {
                s16x8 a0 = *(const s16x8*)&inl[dh][wv * 32 + la + dw][kk * 32 + kb8];
                s16x8 a1 = *(const s16x8*)&inl[dh][wv * 32 + 16 + la + dw][kk * 32 + kb8];
                const u16* wb = wtap + (dh * 3 + dw) * 4096 + kk * 32 + kb8;
                #pragma unroll
                for (int nt = 0; nt < 4; ++nt) {
                    s16x8 bf = *(const s16x8*)(wb + (nt * 16 + la) * 64);
                    acc[0][nt] = __builtin_amdgcn_mfma_f32_16x16x32_bf16(a0, bf, acc[0][nt], 0, 0, 0);
                    acc[1][nt] = __builtin_amdgcn_mfma_f32_16x16x32_bf16(a1, bf, acc[1][nt], 0, 0, 0);
                }
            }
        }
    }
    __syncthreads();   // all inl reads done before overwriting as tl

    // FiLM epilogue into LDS: tl[w][ci] = bf16(dct + qt*(acc + b1))
    #pragma unroll
    for (int mt = 0; mt < 2; ++mt) {
        #pragma unroll
        for (int nt = 0; nt < 4; ++nt) {
            int co = nt * 16 + la;
            int w0 = wv * 32 + mt * 16 + hi * 4;
            float qv = qt[n * 64 + co];
            float bb = b1[co];
            size_t off = ((size_t)(n * 64 + co) * HW) + h * WB + w0;
            float4 d4 = *reinterpret_cast<const float4*>(dct + off);
            tl[w0 + 0][co] = f2bf(d4.x + qv * (acc[mt][nt][0] + bb));
            tl[w0 + 1][co] = f2bf(d4.y + qv * (acc[mt][nt][1] + bb));
            tl[w0 + 2][co] = f2bf(d4.z + qv * (acc[mt][nt][2] + bb));
            tl[w0 + 3][co] = f2bf(d4.w + qv * (acc[mt][nt][3] + bb));
        }
    }
    __syncthreads();

    // 1x1 proj: x[pos][e] = tl[w][:] @ w2b[e][:] + eb2[e]; M=32/wave, N=128, K=64
    f32x4 xa[2][8];
    #pragma unroll
    for (int m = 0; m < 2; ++m)
        #pragma unroll
        for (int j = 0; j < 8; ++j) xa[m][j] = (f32x4){0.f, 0.f, 0.f, 0.f};
    #pragma unroll
    for (int kk = 0; kk < 2; ++kk) {
        s16x8 a0 = *(const s16x8*)&tl[wv * 32 + la][kk * 32 + kb8];
        s16x8 a1 = *(const s16x8*)&tl[wv * 32 + 16 + la][kk * 32 + kb8];
        #pragma unroll
        for (int j = 0; j < 8; ++j) {
            s16x8 bf = *(const s16x8*)(w2b + (j * 16 + la) * 64 + kk * 32 + kb8);
            xa[0][j] = __builtin_amdgcn_mfma_f32_16x16x32_bf16(a0, bf, xa[0][j], 0, 0, 0);
            xa[1][j] = __builtin_amdgcn_mfma_f32_16x16x32_bf16(a1, bf, xa[1][j], 0, 0, 0);
        }
    }
    #pragma unroll
    for (int j = 0; j < 8; ++j) {
        int e = j * 16 + la;
        float be = eb2[e];
        #pragma unroll
        for (int mt = 0; mt < 2; ++mt) {
            int w0 = wv * 32 + mt * 16 + hi * 4;
            size_t pos = (size_t)n * HW + h * WB + w0;
            #pragma unroll
            for (int i = 0; i < 4; ++i)
                x[(pos + i) * EE + e] = xa[mt][j][i] + be;
        }
    }
}

// ============ LN1 + QKV via MFMA ============
__global__ __launch_bounds__(256) void k_qkv2(
    const float* __restrict__ x,
    const float* __restrict__ g, const float* __restrict__ b,
    const u16* __restrict__ wqkvt,
    const float* __restrict__ bq, const float* __restrict__ bk, const float* __restrict__ bv,
    u16* __restrict__ qo, u16* __restrict__ ko, u16* __restrict__ vo)
{
    int pos0 = blockIdx.x * 32;
    int tid = threadIdx.x;
    int lane = tid & 63, wv = tid >> 6;
    __shared__ u16 y0l[32][136];

    {
        int r = tid >> 3, c0 = (tid & 7) * 16;
        const float* xr = x + (size_t)(pos0 + r) * EE + c0;
        float xv[16]; float s1 = 0.f, s2 = 0.f;
        #pragma unroll
        for (int i = 0; i < 16; ++i) { xv[i] = xr[i]; s1 += xv[i]; s2 += xv[i] * xv[i]; }
        #pragma unroll
        for (int off = 1; off < 8; off <<= 1) { s1 += __shfl_xor(s1, off); s2 += __shfl_xor(s2, off); }
        float m = s1 * (1.0f / 128.0f);
        float var = s2 * (1.0f / 128.0f) - m * m;
        float rstd = rsqrtf(var + EPSV);
        #pragma unroll
        for (int i = 0; i < 16; ++i)
            y0l[r][c0 + i] = f2bf((xv[i] - m) * rstd * g[c0 + i] + b[c0 + i]);
    }
    __syncthreads();

    f32x4 acc[2][6];
    #pragma unroll
    for (int m = 0; m < 2; ++m)
        #pragma unroll
        for (int j = 0; j < 6; ++j) acc[m][j] = (f32x4){0.f, 0.f, 0.f, 0.f};
    int la = lane & 15, kb = (lane >> 4) << 3;
    #pragma unroll
    for (int kk = 0; kk < 4; ++kk) {
        s16x8 a0 = *(const s16x8*)&y0l[la][kk * 32 + kb];
        s16x8 a1 = *(const s16x8*)&y0l[16 + la][kk * 32 + kb];
        #pragma unroll
        for (int j = 0; j < 6; ++j) {
            int nt = wv * 6 + j;
            s16x8 bf = *(const s16x8*)(wqkvt + (size_t)(nt * 16 + la) * 128 + kk * 32 + kb);
            acc[0][j] = __builtin_amdgcn_mfma_f32_16x16x32_bf16(a0, bf, acc[0][j], 0, 0, 0);
            acc[1][j] = __builtin_amdgcn_mfma_f32_16x16x32_bf16(a1, bf, acc[1][j], 0, 0, 0);
        }
    }
    #pragma unroll
    for (int j = 0; j < 6; ++j) {
        int nt = wv * 6 + j;
        int mat = nt >> 3;
        int ncol = (nt & 7) * 16 + la;
        float bias = (mat == 0) ? bq[ncol] : (mat == 1) ? bk[ncol] : bv[ncol];
        u16* dst = (mat == 0) ? qo : (mat == 1) ? ko : vo;
        #pragma unroll
        for (int m = 0; m < 2; ++m) {
            #pragma unroll
            for (int i = 0; i < 4; ++i) {
                int row = m * 16 + ((lane >> 4) << 2) + i;
                dst[(size_t)(pos0 + row) * EE + ncol] = f2bf(acc[m][j][i] + bias);
            }
        }
    }
}

// ============ 7x7 sliding-window attention via masked MFMA ============
__global__ __launch_bounds__(256) void k_attn2(
    const u16* __restrict__ q, const u16* __restrict__ k,
    const u16* __restrict__ v, const float* __restrict__ rb,
    float* __restrict__ y2)
{
    int bid = blockIdx.x;
    int hd = bid & 3;
    int wg = (bid >> 2) & 7;
    int hg = (bid >> 5) & 31;
    int n = bid >> 10;
    int h0 = hg * 4, w0 = wg * 16;
    int tid = threadIdx.x;
    int lane = tid & 63, wv = tid >> 6;
    int la = lane & 15, hi = lane >> 4, kb8 = hi * 8;

    __shared__ u16 ksl[224][40];
    __shared__ u16 vtl[32][232];
    __shared__ u16 psl[64][232];
    __shared__ float rbl[PP];

    if (tid < PP) rbl[tid] = rb[hd * PP + tid];

    for (int c = tid; c < 896; c += 256) {
        int kpos = c >> 2, qtr = c & 3;
        int kr = kpos / 22, kc = kpos - kr * 22;
        int hh = h0 + kr - 3, ww = w0 + kc - 3;
        s16x8 kvv = (s16x8){0,0,0,0,0,0,0,0};
        s16x8 vvv = (s16x8){0,0,0,0,0,0,0,0};
        if (kpos < 220 && hh >= 0 && hh < HB && ww >= 0 && ww < WB) {
            size_t base = ((size_t)(n * HW + hh * WB + ww)) * EE + hd * 32 + qtr * 8;
            kvv = *(const s16x8*)(k + base);
            vvv = *(const s16x8*)(v + base);
        }
        *(s16x8*)&ksl[kpos][qtr * 8] = kvv;
        #pragma unroll
        for (int d = 0; d < 8; ++d) vtl[qtr * 8 + d][kpos] = (u16)vvv[d];
    }
    __syncthreads();

    s16x8 qf = *(const s16x8*)(q + ((size_t)(n * HW + (h0 + wv) * WB + w0 + la)) * EE + hd * 32 + kb8);

    f32x4 s[14];
    #pragma unroll
    for (int j = 0; j < 14; ++j) s[j] = (f32x4){0.f, 0.f, 0.f, 0.f};
    #pragma unroll
    for (int j = 0; j < 14; ++j) {
        s16x8 bf = *(const s16x8*)&ksl[j * 16 + la][kb8];
        s[j] = __builtin_amdgcn_mfma_f32_16x16x32_bf16(qf, bf, s[j], 0, 0, 0);
    }

    const float scale = 0.088388347648318447f; // 1/sqrt(128)
    #pragma unroll
    for (int j = 0; j < 14; ++j) {
        int kpos = j * 16 + la;
        int kr = kpos / 22, kc = kpos - kr * 22;
        int di = kr - wv;
        bool rowok = (kpos < 220) && (di >= 0) && (di <= 6);
        #pragma unroll
        for (int i = 0; i < 4; ++i) {
            int qc = hi * 4 + i;
            int dj = kc - qc;
            bool ok = rowok && (dj >= 0) && (dj <= 6);
            s[j][i] = ok ? (s[j][i] * scale + rbl[di * 7 + dj]) : -1e30f;
        }
    }
    float mx[4] = {-1e30f, -1e30f, -1e30f, -1e30f};
    #pragma unroll
    for (int j = 0; j < 14; ++j)
        #pragma unroll
        for (int i = 0; i < 4; ++i) mx[i] = fmaxf(mx[i], s[j][i]);
    #pragma unroll
    for (int off = 1; off < 16; off <<= 1)
        #pragma unroll
        for (int i = 0; i < 4; ++i) mx[i] = fmaxf(mx[i], __shfl_xor(mx[i], off));
    float sum[4] = {0.f, 0.f, 0.f, 0.f};
    #pragma unroll
    for (int j = 0; j < 14; ++j)
        #pragma unroll
        for (int i = 0; i < 4; ++i) {
            float e_ = __expf(s[j][i] - mx[i]);
            s[j][i] = e_; sum[i] += e_;
        }
    #pragma unroll
    for (int off = 1; off < 16; off <<= 1)
        #pragma unroll
        for (int i = 0; i < 4; ++i) sum[i] += __shfl_xor(sum[i], off);
    float inv[4];
    #pragma unroll
    for (int i = 0; i < 4; ++i) inv[i] = 1.0f / sum[i];
    #pragma unroll
    for (int j = 0; j < 14; ++j)
        #pragma unroll
        for (int i = 0; i < 4; ++i)
            psl[wv * 16 + hi * 4 + i][j * 16 + la] = f2bf(s[j][i] * inv[i]);

    f32x4 o[2];
    o[0] = (f32x4){0.f, 0.f, 0.f, 0.f};
    o[1] = (f32x4){0.f, 0.f, 0.f, 0.f};
    #pragma unroll
    for (int kk = 0; kk < 7; ++kk) {
        s16x8 pa = *(const s16x8*)&psl[wv * 16 + la][kk * 32 + kb8];
        #pragma unroll
        for (int nt = 0; nt < 2; ++nt) {
            s16x8 vb = *(const s16x8*)&vtl[nt * 16 + la][kk * 32 + kb8];
            o[nt] = __builtin_amdgcn_mfma_f32_16x16x32_bf16(pa, vb, o[nt], 0, 0, 0);
        }
    }
    #pragma unroll
    for (int nt = 0; nt < 2; ++nt) {
        #pragma unroll
        for (int i = 0; i < 4; ++i) {
            int qc = hi * 4 + i;
            y2[((size_t)(n * HW + (h0 + wv) * WB + w0 + qc)) * EE + hd * 32 + nt * 16 + la] = o[nt][i];
        }
    }
}

// ============ LN2 + FF via MFMA + residual ============
__global__ __launch_bounds__(256) void k_ff2(
    float* __restrict__ x, const float* __restrict__ y2,
    const float* __restrict__ g, const float* __restrict__ b,
    const u16* __restrict__ w1t, const float* __restrict__ b1,
    const u16* __restrict__ w2t, const float* __restrict__ b2)
{
    int pos0 = blockIdx.x * 32;
    int tid = threadIdx.x;
    int lane = tid & 63, wv = tid >> 6;
    __shared__ u16 y3l[32][136];
    __shared__ u16 hl[32][520];

    {
        int r = tid >> 3, c0 = (tid & 7) * 16;
        const float* xr = x + (size_t)(pos0 + r) * EE + c0;
        const float* yr = y2 + (size_t)(pos0 + r) * EE + c0;
        float tv[16]; float s1 = 0.f, s2 = 0.f;
        #pragma unroll
        for (int i = 0; i < 16; ++i) {
            tv[i] = xr[i] + yr[i];
            s1 += tv[i]; s2 += tv[i] * tv[i];
        }
        #pragma unroll
        for (int off = 1; off < 8; off <<= 1) { s1 += __shfl_xor(s1, off); s2 += __shfl_xor(s2, off); }
        float m = s1 * (1.0f / 128.0f);
        float var = s2 * (1.0f / 128.0f) - m * m;
        float rstd = rsqrtf(var + EPSV);
        #pragma unroll
        for (int i = 0; i < 16; ++i)
            y3l[r][c0 + i] = f2bf((tv[i] - m) * rstd * g[c0 + i] + b[c0 + i]);
    }
    __syncthreads();

    int la = lane & 15, kb = (lane >> 4) << 3;

    {
        f32x4 acc[2][8];
        #pragma unroll
        for (int m = 0; m < 2; ++m)
            #pragma unroll
            for (int j = 0; j < 8; ++j) acc[m][j] = (f32x4){0.f, 0.f, 0.f, 0.f};
        int n0 = wv * 128;
        #pragma unroll
        for (int kk = 0; kk < 4; ++kk) {
            s16x8 a0 = *(const s16x8*)&y3l[la][kk * 32 + kb];
            s16x8 a1 = *(const s16x8*)&y3l[16 + la][kk * 32 + kb];
            #pragma unroll
            for (int j = 0; j < 8; ++j) {
                s16x8 bf = *(const s16x8*)(w1t + (size_t)(n0 + j * 16 + la) * 128 + kk * 32 + kb);
                acc[0][j] = __builtin_amdgcn_mfma_f32_16x16x32_bf16(a0, bf, acc[0][j], 0, 0, 0);
                acc[1][j] = __builtin_amdgcn_mfma_f32_16x16x32_bf16(a1, bf, acc[1][j], 0, 0, 0);
            }
        }
        #pragma unroll
        for (int j = 0; j < 8; ++j) {
            int col = n0 + j * 16 + la;
            float bb = b1[col];
            #pragma unroll
            for (int m = 0; m < 2; ++m) {
                #pragma unroll
                for (int i = 0; i < 4; ++i) {
                    int row = m * 16 + ((lane >> 4) << 2) + i;
                    float hx = acc[m][j][i] + bb;
                    hl[row][col] = f2bf(gelu_f(hx));
                }
            }
        }
    }
    __syncthreads();

    {
        f32x4 acc2[2][2];
        #pragma unroll
        for (int m = 0; m < 2; ++m)
            #pragma unroll
            for (int j = 0; j < 2; ++j) acc2[m][j] = (f32x4){0.f, 0.f, 0.f, 0.f};
        int n0 = wv * 32;
        #pragma unroll
        for (int kk = 0; kk < 16; ++kk) {
            s16x8 a0 = *(const s16x8*)&hl[la][kk * 32 + kb];
            s16x8 a1 = *(const s16x8*)&hl[16 + la][kk * 32 + kb];
            #pragma unroll
            for (int j = 0; j < 2; ++j) {
                s16x8 bf = *(const s16x8*)(w2t + (size_t)(n0 + j * 16 + la) * 512 + kk * 32 + kb);
                acc2[0][j] = __builtin_amdgcn_mfma_f32_16x16x32_bf16(a0, bf, acc2[0][j], 0, 0, 0);
                acc2[1][j] = __builtin_amdgcn_mfma_f32_16x16x32_bf16(a1, bf, acc2[1][j], 0, 0, 0);
            }
        }
        #pragma unroll
        for (int j = 0; j < 2; ++j) {
            int col = n0 + j * 16 + la;
            float bb = b2[col];
            #pragma unroll
            for (int m = 0; m < 2; ++m) {
                #pragma unroll
                for (int i = 0; i < 4; ++i) {
                    int row = m * 16 + ((lane >> 4) << 2) + i;
                    size_t grow = (size_t)(pos0 + row) * EE + col;
                    x[grow] = y2[grow] + acc2[m][j][i] + bb;
                }
            }
        }
    }
}

// ============ Decoder via MFMA: out = dct + (x @ dec_w^T + dec_b)*qt ============
// block = 64 positions; waves split 64 co into 4 n-tiles; K=128.
__global__ __launch_bounds__(256) void k_dec2(
    const float* __restrict__ x, const float* __restrict__ dct,
    const float* __restrict__ qt, const u16* __restrict__ dwb,
    const float* __restrict__ bd, float* __restrict__ out)
{
    int pos0 = blockIdx.x * 64;
    int n = pos0 >> 14;
    int hw0 = pos0 & 16383;
    int tid = threadIdx.x;
    int lane = tid & 63, wv = tid >> 6;
    int la = lane & 15, hi = lane >> 4, kb8 = hi * 8;
    __shared__ u16 al[64][136];

    for (int it = 0; it < 32; ++it) {
        int idx = it * 256 + tid;
        int r = idx >> 7, c = idx & 127;
        al[r][c] = f2bf(x[(size_t)(pos0 + r) * EE + c]);
    }
    __syncthreads();

    f32x4 acc[4];
    #pragma unroll
    for (int m = 0; m < 4; ++m) acc[m] = (f32x4){0.f, 0.f, 0.f, 0.f};
    #pragma unroll
    for (int kk = 0; kk < 4; ++kk) {
        s16x8 bf = *(const s16x8*)(dwb + (wv * 16 + la) * 128 + kk * 32 + kb8);
        #pragma unroll
        for (int m = 0; m < 4; ++m) {
            s16x8 a = *(const s16x8*)&al[m * 16 + la][kk * 32 + kb8];
            acc[m] = __builtin_amdgcn_mfma_f32_16x16x32_bf16(a, bf, acc[m], 0, 0, 0);
        }
    }
    int co = wv * 16 + la;
    float qv = qt[n * 64 + co];
    float bb = bd[co];
    #pragma unroll
    for (int m = 0; m < 4; ++m) {
        int p = m * 16 + hi * 4;
        size_t off = ((size_t)(n * 64 + co)) * HW + hw0 + p;
        float4 d4 = *reinterpret_cast<const float4*>(dct + off);
        float4 r;
        r.x = d4.x + (acc[m][0] + bb) * qv;
        r.y = d4.y + (acc[m][1] + bb) * qv;
        r.z = d4.z + (acc[m][2] + bb) * qv;
        r.w = d4.w + (acc[m][3] + bb) * qv;
        *reinterpret_cast<float4*>(out + off) = r;
    }
}

extern "C" void kernel_launch(void* const* d_in, const int* in_sizes, int n_in,
                              void* d_out, int out_size, void* d_ws, size_t ws_size,
                              hipStream_t stream) {
    const float* dct  = (const float*)d_in[0];
    const float* qt   = (const float*)d_in[1];
    const float* ec1w = (const float*)d_in[2];
    const float* ec1b = (const float*)d_in[3];
    const float* ec2w = (const float*)d_in[4];
    const float* ec2b = (const float*)d_in[5];
    const float* ln1g = (const float*)d_in[6];
    const float* ln1b = (const float*)d_in[7];
    const float* qw   = (const float*)d_in[8];
    const float* qb   = (const float*)d_in[9];
    const float* kw   = (const float*)d_in[10];
    const float* kb   = (const float*)d_in[11];
    const float* vw   = (const float*)d_in[12];
    const float* vb   = (const float*)d_in[13];
    const float* rb   = (const float*)d_in[14];
    const float* ln2g = (const float*)d_in[15];
    const float* ln2b = (const float*)d_in[16];
    const float* fw1  = (const float*)d_in[17];
    const float* fb1  = (const float*)d_in[18];
    const float* fw2  = (const float*)d_in[19];
    const float* fb2  = (const float*)d_in[20];
    const float* dw   = (const float*)d_in[21];
    const float* db   = (const float*)d_in[22];

    char* ws = (char*)d_ws;
    float* xbuf  = (float*)ws;                         // 67108864 B
    float* y2buf = (float*)(ws + 67108864);            // 67108864 B
    u16*   qbuf  = (u16*)(ws + 134217728);             // 33554432 B
    u16*   kbuf  = (u16*)(ws + 167772160);             // 33554432 B
    u16*   vbuf  = (u16*)(ws + 201326592);             // 33554432 B
    size_t woff = 234881024;
    u16* wqkvt = (u16*)(ws + woff);                    // 393216 B
    u16* w1t   = (u16*)(ws + woff + 393216);           // 524288 B
    u16* w2t   = (u16*)(ws + woff + 917504);           // 524288 B
    u16* wtap  = (u16*)(ws + woff + 1441792);          // 73728 B
    u16* w2b   = (u16*)(ws + woff + 1515520);          // 16384 B
    u16* dwb   = (u16*)(ws + woff + 1531904);          // 16384 B

    k_prep_qkvff<<<dim3(2816), dim3(256), 0, stream>>>(qw, kw, vw, fw1, fw2, wqkvt, w1t, w2t);
    k_prep_conv<<<dim3(208), dim3(256), 0, stream>>>(ec1w, ec2w, dw, wtap, w2b, dwb);

    k_enc_conv3<<<dim3(NB * HB), dim3(256), 0, stream>>>(dct, qt, wtap, ec1b, w2b, ec2b, xbuf);
    for (int l = 0; l < NLAY; ++l) {
        k_qkv2<<<dim3(NPOS / 32), dim3(256), 0, stream>>>(
            xbuf, ln1g + l * EE, ln1b + l * EE,
            wqkvt + l * 49152,
            qb + l * EE, kb + l * EE, vb + l * EE,
            qbuf, kbuf, vbuf);
        k_attn2<<<dim3(NB * 32 * 8 * 4), dim3(256), 0, stream>>>(
            qbuf, kbuf, vbuf, rb + l * NHD * PP, y2buf);
        k_ff2<<<dim3(NPOS / 32), dim3(256), 0, stream>>>(
            xbuf, y2buf, ln2g + l * EE, ln2b + l * EE,
            w1t + l * 65536, fb1 + l * DFF,
            w2t + l * 65536, fb2 + l * EE);
    }
    k_dec2<<<dim3(NPOS / 64), dim3(256), 0, stream>>>(
        xbuf, dct, qt, dwb, db, (float*)d_out);
}